// Round 11
// baseline (3080.912 us; speedup 1.0000x reference)
//
#include <hip/hip_runtime.h>
#include <hip/hip_bf16.h>
#include <math.h>

namespace {

constexpr int D    = 768;
constexpr int NH   = 12;
constexpr int PTOT = 257;
constexpr int NB   = 2;
constexpr int TT   = 16;
constexpr int NTOK = NB * TT * PTOT;   // 8224
constexpr int NPAT = NB * TT * 256;    // 8192
constexpr int QKVD = 3 * D;            // 2304

typedef short short8  __attribute__((ext_vector_type(8)));
typedef float float4v __attribute__((ext_vector_type(4)));

__device__ __forceinline__ float bf2f(unsigned short u) {
  unsigned v = ((unsigned)u) << 16;
  float f; __builtin_memcpy(&f, &v, 4); return f;
}
__device__ __forceinline__ unsigned short f2bf(float f) {
  unsigned u; __builtin_memcpy(&u, &f, 4);
  u += 0x7FFFu + ((u >> 16) & 1u);   // RNE
  return (unsigned short)(u >> 16);
}

// async global->LDS, 16B per lane, dst = uniform base + lane*16
__device__ __forceinline__ void gload_lds16(const void* g, void* l) {
  __builtin_amdgcn_global_load_lds((const __attribute__((address_space(1))) void*)g,
                                   (__attribute__((address_space(3))) void*)l, 16, 0, 0);
}

// ---------------- unfold x -> xpb (8192 x 768) bf16 ----------------
__global__ __launch_bounds__(256) void unfold_kernel(const float* __restrict__ x,
                                                     unsigned short* __restrict__ xpb) {
  int idx = blockIdx.x * 256 + threadIdx.x;
  if (idx >= NPAT * D) return;
  int f  = idx % D;
  int pg = idx / D;
  int c = f >> 8;
  int r = f & 255;
  int i = r >> 4, j = r & 15;
  int nt = pg >> 8;
  int s  = pg & 255;
  int hp = s >> 4, wp = s & 15;
  xpb[idx] = f2bf(x[(size_t)(nt * 3 + c) * 65536 + (size_t)(hp * 16 + i) * 256 + (wp * 16 + j)]);
}

// ---------------- patch_w (768x768, already BT-layout) fp32 -> bf16 ----------------
__global__ __launch_bounds__(256) void cast_pw(const float* __restrict__ pw,
                                               unsigned short* __restrict__ pwb) {
  int idx = blockIdx.x * 256 + threadIdx.x;
  if (idx >= D * D) return;
  pwb[idx] = f2bf(pw[idx]);
}

// ---------------- weight transpose + fp32->bf16: W[L][768][N] -> WT[L][N][768] ----
__global__ __launch_bounds__(256) void wconv(const float* __restrict__ W,
                                             unsigned short* __restrict__ WT, int N) {
  __shared__ float tile[32][33];
  int l = blockIdx.z;
  const float* w = W + (size_t)l * 768 * N;
  unsigned short* wt = WT + (size_t)l * 768 * N;
  int n0 = blockIdx.x * 32, k0 = blockIdx.y * 32;
  int t = threadIdx.x;
  {
    int r = t >> 3, c4 = (t & 7) * 4;
    float4 v = *(const float4*)(w + (size_t)(k0 + r) * N + n0 + c4);
    tile[r][c4 + 0] = v.x; tile[r][c4 + 1] = v.y;
    tile[r][c4 + 2] = v.z; tile[r][c4 + 3] = v.w;
  }
  __syncthreads();
  {
    int rn = t >> 3, ck = (t & 7) * 4;
    ushort4 o;
    o.x = f2bf(tile[ck + 0][rn]); o.y = f2bf(tile[ck + 1][rn]);
    o.z = f2bf(tile[ck + 2][rn]); o.w = f2bf(tile[ck + 3][rn]);
    *(ushort4*)(wt + (size_t)(n0 + rn) * 768 + k0 + ck) = o;
  }
}

// ---------------- assemble h (fp32) + hb (bf16 mirror) ----------------
// patch_b is already folded into tok by the patch-embed GEMM's bias path.
__global__ __launch_bounds__(256) void assemble_kernel(const float* __restrict__ tok,
    const float* __restrict__ cls,
    const float* __restrict__ pos, const float* __restrict__ tim,
    float* __restrict__ h, unsigned short* __restrict__ hb) {
  int idx = blockIdx.x * 256 + threadIdx.x;
  if (idx >= NTOK * D) return;
  int d = idx % D;
  int tokid = idx / D;
  int p  = tokid % PTOT;
  int nt = tokid / PTOT;
  int t  = nt % TT;
  float v = pos[p * D + d] + tim[t * D + d];
  if (p == 0) v += cls[d];
  else        v += tok[(size_t)(nt * 256 + (p - 1)) * D + d];
  h[idx] = v;
  hb[idx] = f2bf(v);
}

// ---------------- bf16 MFMA GEMM, 2-phase pipelined + XCD swizzle + bounce epilogue --
// (128x128 tile; used for proj / patch-embed shapes, N=768.)
// mode 0: Cb = result (bf16).  mode 1: Hf += result (fp32); Hb = bf16(new Hf).
// mode 2: Hf = result (fp32).
__global__ __launch_bounds__(256) void gemm_bf16(
    const unsigned short* __restrict__ A,
    const unsigned short* __restrict__ BT,
    const float* __restrict__ bias,
    unsigned short* __restrict__ Cb,
    float* __restrict__ Hf,
    unsigned short* __restrict__ Hb,
    int M, int N, int mode)
{
  constexpr int K = 768;
  constexpr int NT = K / 32;           // 24 K-steps
  __shared__ unsigned short smem[16384];   // 32 KB: As(8K) | Bs(8K) shorts; epilogue: Ct[128][128]
  auto As = (unsigned short (*)[128][32])smem;
  auto Bs = (unsigned short (*)[128][32])(smem + 8192);
  auto Ct = (unsigned short (*)[128])smem;
  int tid = threadIdx.x;

  // bijective XCD-aware remap of the flat (dispatch-order) workgroup id (m204)
  int nwg = gridDim.x * gridDim.y;
  int wg  = blockIdx.y * gridDim.x + blockIdx.x;   // x-fastest dispatch order
  int qq  = nwg >> 3, rr = nwg & 7;
  int xcd = wg & 7, bidx = wg >> 3;
  int newid = (xcd < rr ? xcd * (qq + 1) : rr * (qq + 1) + (xcd - rr) * qq) + bidx;
  int m0 = (newid / gridDim.x) * 128;
  int n0 = (newid % gridDim.x) * 128;

  int w = tid >> 6, lane = tid & 63;
  int quad = lane >> 4, l16 = lane & 15;
  int wm = (w & 1) * 64, wn = (w >> 1) * 64;
  const int lrow = lane >> 2;          // 0..15 within an issue
  const int scol = (lane & 3) * 8;     // shorts
  float4v acc[4][4] = {};

  // hoisted per-lane staging pointers (advance by t*32 shorts per K-step)
  const unsigned short* gA0 = A + (size_t)min(m0 + w * 32 + lrow, M - 1) * K + scol;
  const unsigned short* gA1 = A + (size_t)min(m0 + w * 32 + 16 + lrow, M - 1) * K + scol;
  const unsigned short* gB0 = BT + (size_t)(n0 + w * 32 + lrow) * K + scol;
  const unsigned short* gB1 = BT + (size_t)(n0 + w * 32 + 16 + lrow) * K + scol;

  auto STAGE = [&](int buf, int t) {
    int kk = t * 32;
    gload_lds16(gA0 + kk, &As[buf][w * 32][0]);
    gload_lds16(gA1 + kk, &As[buf][w * 32 + 16][0]);
    gload_lds16(gB0 + kk, &Bs[buf][w * 32][0]);
    gload_lds16(gB1 + kk, &Bs[buf][w * 32 + 16][0]);
  };
  auto COMPUTE = [&](int buf) {
    short8 af[4], bfr[4];
    #pragma unroll
    for (int i = 0; i < 4; ++i) {
      af[i]  = *(const short8*)&As[buf][wm + i * 16 + l16][quad * 8];
      bfr[i] = *(const short8*)&Bs[buf][wn + i * 16 + l16][quad * 8];
    }
    __builtin_amdgcn_s_setprio(1);
    #pragma unroll
    for (int i = 0; i < 4; ++i)
      #pragma unroll
      for (int j = 0; j < 4; ++j)
        acc[i][j] = __builtin_amdgcn_mfma_f32_16x16x32_bf16(af[i], bfr[j], acc[i][j], 0, 0, 0);
    __builtin_amdgcn_s_setprio(0);
  };

  STAGE(0, 0);
  __syncthreads();                       // drains prologue loads
  for (int t = 0; t < NT; t += 2) {
    STAGE(1, t + 1);                     // prefetch next tile (in flight during MFMA)
    COMPUTE(0);
    __syncthreads();                     // drain buf1 loads; all waves done reading buf0
    if (t + 2 < NT) STAGE(0, t + 2);
    COMPUTE(1);
    __syncthreads();                     // drain buf0 loads; all waves done reading buf1
  }

  if (mode == 2) {
    // fp32 direct stores: 16-lane f32 segments = 64B aligned, already coalesced
    #pragma unroll
    for (int j = 0; j < 4; ++j) {
      int col = n0 + wn + j * 16 + l16;
      float bv = bias[col];
      #pragma unroll
      for (int i = 0; i < 4; ++i) {
        #pragma unroll
        for (int r = 0; r < 4; ++r) {
          int row = m0 + wm + i * 16 + quad * 4 + r;
          if (row < M) Hf[(size_t)row * N + col] = acc[i][j][r] + bv;
        }
      }
    }
    return;
  }

  // ---- phase A: fragments -> Ct (quad-XOR chunk swizzle), mode 1 also RMWs Hf ----
  #pragma unroll
  for (int j = 0; j < 4; ++j) {
    int col = wn + j * 16 + l16;                   // tile col 0..127
    float bv = bias[n0 + col];
    int pc = (((col >> 3) ^ quad) << 3) | (col & 7);  // swizzled phys col
    #pragma unroll
    for (int i = 0; i < 4; ++i) {
      #pragma unroll
      for (int r = 0; r < 4; ++r) {
        int row = wm + i * 16 + quad * 4 + r;      // tile row 0..127 ; (row>>2)&3 == quad
        float v = acc[i][j][r] + bv;
        unsigned short ov;
        if (mode == 1) {
          size_t off = (size_t)(m0 + row) * N + (n0 + col);
          if (m0 + row < M) {
            float nv = Hf[off] + v;
            Hf[off] = nv;
            ov = f2bf(nv);
          } else ov = 0;
        } else {
          ov = f2bf(v);
        }
        Ct[row][pc] = ov;
      }
    }
  }
  __syncthreads();
  // ---- phase B: coalesced bounce-out, 16B/lane in 256B-contiguous runs ----
  unsigned short* Ob = (mode == 0) ? Cb : Hb;
  #pragma unroll
  for (int e = 0; e < 8; ++e) {
    int c    = e * 256 + tid;
    int trow = c >> 4, tch = c & 15;
    int grow = m0 + trow;
    if (grow < M) {
      int pch = tch ^ ((trow >> 2) & 3);
      *(uint4*)(Ob + (size_t)grow * N + n0 + tch * 8) = *(const uint4*)&Ct[trow][pch * 8];
    }
  }
}

// ---------------- HIGH-OCCUPANCY bf16 GEMM: 64x128 tile, BK=32, mode-0 (qkv) ------
// R11: occupancy-FIRST variant. R3/R5/R6/R10 all lost residency chasing per-step
// efficiency and regressed; this goes the other way. 4 waves, per-wave 32x64
// (acc[2][4] ~= 75 VGPR), LDS 24 KB -> static ~6 blocks/CU (vs ~2 measured at
// 128^2). Grid 18 x 129 = 2322 blocks = 9/CU. Same 2-phase barrier semantics,
// same staging pattern, same XCD swizzle, same bounce epilogue (Ct[64][128]).
// Bet: in the HBM-latency-bound regime, 3x resident waves beats 2x fewer
// barrier events.
__global__ __launch_bounds__(256) void gemm_bf16_h64(
    const unsigned short* __restrict__ A,
    const unsigned short* __restrict__ BT,
    const float* __restrict__ bias,
    unsigned short* __restrict__ Cb,
    int M, int N)
{
  constexpr int K = 768;
  constexpr int NT = K / 32;           // 24 K-steps
  __shared__ unsigned short smem[12288];   // 24 KB: As 2*64*32 | Bs 2*128*32; epi: Ct[64][128]
  auto As = (unsigned short (*)[64][32])smem;
  auto Bs = (unsigned short (*)[128][32])(smem + 4096);
  auto Ct = (unsigned short (*)[128])smem;
  int tid = threadIdx.x;

  int nwg = gridDim.x * gridDim.y;
  int wg  = blockIdx.y * gridDim.x + blockIdx.x;
  int qq  = nwg >> 3, rr = nwg & 7;
  int xcd = wg & 7, bidx = wg >> 3;
  int newid = (xcd < rr ? xcd * (qq + 1) : rr * (qq + 1) + (xcd - rr) * qq) + bidx;
  int m0 = (newid / gridDim.x) * 64;
  int n0 = (newid % gridDim.x) * 128;

  int w = tid >> 6, lane = tid & 63;
  int quad = lane >> 4, l16 = lane & 15;
  int wm = (w & 1) * 32, wn = (w >> 1) * 64;   // 2M x 2N waves, 32x64 per wave
  const int lrow = lane >> 2;
  const int scol = (lane & 3) * 8;
  float4v acc[2][4] = {};

  const unsigned short* gA0 = A + (size_t)min(m0 + w * 16 + lrow, M - 1) * K + scol;
  const unsigned short* gB0 = BT + (size_t)(n0 + w * 32 + lrow) * K + scol;
  const unsigned short* gB1 = BT + (size_t)(n0 + w * 32 + 16 + lrow) * K + scol;

  auto STAGE = [&](int buf, int t) {
    int kk = t * 32;
    gload_lds16(gA0 + kk, &As[buf][w * 16][0]);
    gload_lds16(gB0 + kk, &Bs[buf][w * 32][0]);
    gload_lds16(gB1 + kk, &Bs[buf][w * 32 + 16][0]);
  };
  auto COMPUTE = [&](int buf) {
    short8 af[2], bfr[4];
    #pragma unroll
    for (int i = 0; i < 2; ++i)
      af[i] = *(const short8*)&As[buf][wm + i * 16 + l16][quad * 8];
    #pragma unroll
    for (int j = 0; j < 4; ++j)
      bfr[j] = *(const short8*)&Bs[buf][wn + j * 16 + l16][quad * 8];
    __builtin_amdgcn_s_setprio(1);
    #pragma unroll
    for (int i = 0; i < 2; ++i)
      #pragma unroll
      for (int j = 0; j < 4; ++j)
        acc[i][j] = __builtin_amdgcn_mfma_f32_16x16x32_bf16(af[i], bfr[j], acc[i][j], 0, 0, 0);
    __builtin_amdgcn_s_setprio(0);
  };

  STAGE(0, 0);
  __syncthreads();
  for (int t = 0; t < NT; t += 2) {
    STAGE(1, t + 1);
    COMPUTE(0);
    __syncthreads();
    if (t + 2 < NT) STAGE(0, t + 2);
    COMPUTE(1);
    __syncthreads();
  }

  // ---- bounce epilogue: fragments -> Ct (quad-XOR swizzle) -> coalesced stores ----
  #pragma unroll
  for (int j = 0; j < 4; ++j) {
    int col = wn + j * 16 + l16;                   // 0..127
    float bv = bias[n0 + col];
    int pc = (((col >> 3) ^ quad) << 3) | (col & 7);
    #pragma unroll
    for (int i = 0; i < 2; ++i) {
      #pragma unroll
      for (int r = 0; r < 4; ++r) {
        int row = wm + i * 16 + quad * 4 + r;      // 0..63 ; (row>>2)&3 == quad
        Ct[row][pc] = f2bf(acc[i][j][r] + bv);
      }
    }
  }
  __syncthreads();
  #pragma unroll
  for (int e = 0; e < 4; ++e) {
    int c = e * 256 + tid;                         // 0..1023
    int trow = c >> 4, tch = c & 15;
    int grow = m0 + trow;
    if (grow < M) {
      int pch = tch ^ ((trow >> 2) & 3);
      *(uint4*)(Cb + (size_t)grow * N + n0 + tch * 8) = *(const uint4*)&Ct[trow][pch * 8];
    }
  }
}

// ---------------- spatial attention (bf16 MFMA, flash-tiled) ----------------
// R9: one Q-TILE PER BLOCK (grid x5 = 1920; consecutive blocks share (nt,head)
// K/V in L2). Per-wave just-in-time P slice Psl[4][16][72] replaces the 38KB
// full-Ps: LDS 56.3 -> 27.6 KB. V-transpose writes ROTATED per lane
// (conflict-free; was 16-way = 11.1M conflict cycles).
__global__ __launch_bounds__(256) void attn_spatial3(
    const unsigned short* __restrict__ qkv,
    unsigned short* __restrict__ o)
{
  __shared__ unsigned short Qs[64][72];
  __shared__ unsigned short KVs[64][72];   // K rows (QK phase) / V^T dims (PV phase)
  __shared__ unsigned short Psl[4][16][72];  // per-wave P slice for one 64-k V tile
  int tid = threadIdx.x;
  int w = tid >> 6, lane = tid & 63;
  int quad = lane >> 4, l16 = lane & 15;
  int bid = blockIdx.x;
  int bh = bid / 5, qt = bid % 5;          // 5 q-tiles per (nt,head)
  int nt = bh / NH, head = bh % NH;
  int q0 = qt * 64;
  size_t base = (size_t)nt * PTOT;
  const unsigned short* Qg = qkv + head * 64;
  const unsigned short* Kg = qkv + 768 + head * 64;
  const unsigned short* Vg = qkv + 1536 + head * 64;

  // ---- stage Q once (vectorized) ----
  #pragma unroll
  for (int e = 0; e < 2; ++e) {
    int chunk = e * 256 + tid;
    int row = chunk >> 3, off = (chunk & 7) * 8;
    int qr = min(q0 + row, PTOT - 1);
    *(uint4*)&Qs[row][off] = *(const uint4*)(Qg + (base + qr) * (size_t)QKVD + off);
  }
  __syncthreads();
  int qrow = w * 16 + l16;
  short8 qa0 = *(const short8*)&Qs[qrow][quad * 8];
  short8 qa1 = *(const short8*)&Qs[qrow][32 + quad * 8];

  // ---- QK^T: 5 K tiles, scores in registers ----
  float4v st[17];
  #pragma unroll
  for (int kc = 0; kc < 5; ++kc) {
    __syncthreads();
    #pragma unroll
    for (int e = 0; e < 2; ++e) {
      int chunk = e * 256 + tid;
      int row = chunk >> 3, off = (chunk & 7) * 8;
      int kr = min(kc * 64 + row, PTOT - 1);
      *(uint4*)&KVs[row][off] = *(const uint4*)(Kg + (base + kr) * (size_t)QKVD + off);
    }
    __syncthreads();
    #pragma unroll
    for (int tt = 0; tt < 4; ++tt) {
      int t = kc * 4 + tt;
      if (t < 17) {
        short8 kb0 = *(const short8*)&KVs[tt * 16 + l16][quad * 8];
        short8 kb1 = *(const short8*)&KVs[tt * 16 + l16][32 + quad * 8];
        float4v a = {0.f, 0.f, 0.f, 0.f};
        a = __builtin_amdgcn_mfma_f32_16x16x32_bf16(qa0, kb0, a, 0, 0, 0);
        a = __builtin_amdgcn_mfma_f32_16x16x32_bf16(qa1, kb1, a, 0, 0, 0);
        st[t] = a;
      }
    }
  }
  if (l16 >= 1) {
    st[16][0] = -1e30f; st[16][1] = -1e30f; st[16][2] = -1e30f; st[16][3] = -1e30f;
  }
  // ---- softmax (1/8 scale folded into exp; monotone) ----
  float mx[4] = {-1e30f, -1e30f, -1e30f, -1e30f};
  #pragma unroll
  for (int t = 0; t < 17; ++t)
    #pragma unroll
    for (int r = 0; r < 4; ++r) mx[r] = fmaxf(mx[r], st[t][r]);
  #pragma unroll
  for (int off = 1; off < 16; off <<= 1)
    #pragma unroll
    for (int r = 0; r < 4; ++r) mx[r] = fmaxf(mx[r], __shfl_xor(mx[r], off));
  float sm[4] = {0.f, 0.f, 0.f, 0.f};
  #pragma unroll
  for (int t = 0; t < 17; ++t)
    #pragma unroll
    for (int r = 0; r < 4; ++r) {
      float e = __expf((st[t][r] - mx[r]) * 0.125f);
      st[t][r] = e;
      sm[r] += e;
    }
  #pragma unroll
  for (int off = 1; off < 16; off <<= 1)
    #pragma unroll
    for (int r = 0; r < 4; ++r) sm[r] += __shfl_xor(sm[r], off);
  float linv[4];
  #pragma unroll
  for (int r = 0; r < 4; ++r) linv[r] = 1.f / sm[r];

  // ---- PV: 5 V tiles; per-tile JIT P slice (wave-private, no extra barriers) ----
  float4v oacc[4] = {};
  #pragma unroll
  for (int vc = 0; vc < 5; ++vc) {
    __syncthreads();
    // V transposed stage with lane-rotated write order (conflict-free)
    #pragma unroll
    for (int e = 0; e < 2; ++e) {
      int chunk = e * 256 + tid;
      int row = chunk >> 3;
      int oo  = chunk & 7;
      int off = oo * 8;
      int vr = min(vc * 64 + row, PTOT - 1);
      uint4 u = *(const uint4*)(Vg + (base + vr) * (size_t)QKVD + off);
      #pragma unroll
      for (int s = 0; s < 8; ++s) {
        int idx = (oo + s) & 7;
        unsigned sel01 = (idx & 2) ? u.y : u.x;
        unsigned sel23 = (idx & 2) ? u.w : u.z;
        unsigned dw    = (idx & 4) ? sel23 : sel01;
        unsigned short val = (idx & 1) ? (unsigned short)(dw >> 16) : (unsigned short)dw;
        KVs[off + idx][row] = val;
      }
    }
    // P slice for this 64-k tile (wave-private; lgkm ordering suffices)
    #pragma unroll
    for (int tt = 0; tt < 4; ++tt) {
      int t = vc * 4 + tt;
      #pragma unroll
      for (int r = 0; r < 4; ++r) {
        unsigned short pv = 0;
        if (t < 17) pv = f2bf(st[t][r]);
        Psl[w][quad * 4 + r][tt * 16 + l16] = pv;
      }
    }
    __syncthreads();
    int ksmax = (vc == 4) ? 1 : 2;
    #pragma unroll
    for (int ks = 0; ks < 2; ++ks) {
      if (ks < ksmax) {
        short8 pa = *(const short8*)&Psl[w][l16][ks * 32 + quad * 8];
        #pragma unroll
        for (int j = 0; j < 4; ++j) {
          short8 vb = *(const short8*)&KVs[j * 16 + l16][ks * 32 + quad * 8];
          oacc[j] = __builtin_amdgcn_mfma_f32_16x16x32_bf16(pa, vb, oacc[j], 0, 0, 0);
        }
      }
    }
  }
  // ---- store ----
  #pragma unroll
  for (int r = 0; r < 4; ++r) {
    int qg = q0 + w * 16 + quad * 4 + r;
    if (qg < PTOT) {
      #pragma unroll
      for (int j = 0; j < 4; ++j)
        o[(base + qg) * (size_t)D + head * 64 + j * 16 + l16] = f2bf(oacc[j][r] * linv[r]);
    }
  }
}

// ---------------- temporal attention v2: one wave per (n,head,p), MFMA 16x16 ----
// grid = 6168/4 blocks, 4 waves/block, wave-private LDS, NO barriers.
__global__ __launch_bounds__(256) void attn_temporal2(const unsigned short* __restrict__ qkv,
                                                      unsigned short* __restrict__ o) {
  __shared__ unsigned short Ps[4][16][32];   // P padded to K=32 (cols 16..31 zero)
  __shared__ unsigned short VT[4][64][32];   // V^T padded to K=32
  int tid = threadIdx.x;
  int w = tid >> 6, lane = tid & 63;
  int quad = lane >> 4, l16 = lane & 15;
  int s = blockIdx.x * 4 + w;                // 0..6167
  int p  = s % PTOT;
  int nh = s / PTOT;
  int n = nh / NH, head = nh % NH;

  // zero k-padding (wave-local)
  {
    ushort4 z = {0, 0, 0, 0};
    *(ushort4*)&Ps[w][lane >> 2][16 + (lane & 3) * 4] = z;
    *(uint4*)&VT[w][lane][16] = (uint4){0, 0, 0, 0};
    *(uint4*)&VT[w][lane][24] = (uint4){0, 0, 0, 0};
  }

  const size_t rstride = (size_t)PTOT * QKVD;   // elements between consecutive t
  const unsigned short* base0 = qkv + ((size_t)(n * TT) * PTOT + p) * QKVD + head * 64;

  // Q/K fragments straight from global (row t = l16, 16B chunks)
  const unsigned short* qrow = base0 + (size_t)l16 * rstride;
  short8 qa0 = *(const short8*)(qrow + quad * 8);
  short8 qa1 = *(const short8*)(qrow + 32 + quad * 8);
  const unsigned short* krow = qrow + 768;
  short8 kb0 = *(const short8*)(krow + quad * 8);
  short8 kb1 = *(const short8*)(krow + 32 + quad * 8);

  float4v sc = {0.f, 0.f, 0.f, 0.f};
  sc = __builtin_amdgcn_mfma_f32_16x16x32_bf16(qa0, kb0, sc, 0, 0, 0);
  sc = __builtin_amdgcn_mfma_f32_16x16x32_bf16(qa1, kb1, sc, 0, 0, 0);

  // softmax across the 16 lanes of each quad (rows quad*4+r, cols l16)
  float e4[4], mx[4], sm[4];
  #pragma unroll
  for (int r = 0; r < 4; ++r) mx[r] = sc[r] * 0.125f;
  #pragma unroll
  for (int off = 1; off < 16; off <<= 1)
    #pragma unroll
    for (int r = 0; r < 4; ++r) mx[r] = fmaxf(mx[r], __shfl_xor(mx[r], off));
  #pragma unroll
  for (int r = 0; r < 4; ++r) { e4[r] = __expf(sc[r] * 0.125f - mx[r]); sm[r] = e4[r]; }
  #pragma unroll
  for (int off = 1; off < 16; off <<= 1)
    #pragma unroll
    for (int r = 0; r < 4; ++r) sm[r] += __shfl_xor(sm[r], off);
  float linv[4];
  #pragma unroll
  for (int r = 0; r < 4; ++r) linv[r] = 1.f / sm[r];

  // P -> LDS (A-layout source)
  #pragma unroll
  for (int r = 0; r < 4; ++r) Ps[w][quad * 4 + r][l16] = f2bf(e4[r]);

  // V^T -> LDS: lane covers V row t'=l16, dims quad*16..quad*16+15
  {
    const unsigned short* vrow = qrow + 1536 + quad * 16;
    uint4 v0 = *(const uint4*)vrow;
    uint4 v1 = *(const uint4*)(vrow + 8);
    const unsigned short* pv0 = (const unsigned short*)&v0;
    const unsigned short* pv1 = (const unsigned short*)&v1;
    #pragma unroll
    for (int i = 0; i < 8; ++i) VT[w][quad * 16 + i][l16]     = pv0[i];
    #pragma unroll
    for (int i = 0; i < 8; ++i) VT[w][quad * 16 + 8 + i][l16] = pv1[i];
  }

  // PV: O[16 q][64 d] = P @ V, 4 MFMAs over d-tiles
  short8 pa = *(const short8*)&Ps[w][l16][quad * 8];
  float4v oacc[4];
  #pragma unroll
  for (int j = 0; j < 4; ++j) {
    short8 vb = *(const short8*)&VT[w][j * 16 + l16][quad * 8];
    float4v z = {0.f, 0.f, 0.f, 0.f};
    oacc[j] = __builtin_amdgcn_mfma_f32_16x16x32_bf16(pa, vb, z, 0, 0, 0);
  }

  // store: row t = quad*4+r, col head*64 + j*16 + l16
  #pragma unroll
  for (int r = 0; r < 4; ++r) {
    size_t orow = ((size_t)(n * TT + quad * 4 + r) * PTOT + p) * D + head * 64;
    #pragma unroll
    for (int j = 0; j < 4; ++j)
      o[orow + j * 16 + l16] = f2bf(oacc[j][r] * linv[r]);
  }
}

// ---------------- final LN on cls rows + mean over t + head ----------------
__device__ __forceinline__ float block_sum(float v, float* lds) {
  #pragma unroll
  for (int off = 32; off; off >>= 1) v += __shfl_down(v, off);
  __syncthreads();
  if ((threadIdx.x & 63) == 0) lds[threadIdx.x >> 6] = v;
  __syncthreads();
  return lds[0] + lds[1] + lds[2] + lds[3];
}

__global__ __launch_bounds__(256) void head_kernel(const float* __restrict__ h,
    const float* __restrict__ g, const float* __restrict__ b,
    const float* __restrict__ hw, const float* __restrict__ hb,
    float* __restrict__ out) {
  __shared__ float lds[4];
  int n = blockIdx.x, tid = threadIdx.x;
  float logit = 0.f;
  for (int t = 0; t < TT; ++t) {
    const float* row = h + (size_t)((n * TT + t) * PTOT) * D;
    float v[3]; float s = 0.f;
    #pragma unroll
    for (int i = 0; i < 3; ++i) { v[i] = row[tid + 256 * i]; s += v[i]; }
    s = block_sum(s, lds);
    float mu = s * (1.f / D);
    float s2 = 0.f;
    #pragma unroll
    for (int i = 0; i < 3; ++i) { float d0 = v[i] - mu; s2 += d0 * d0; }
    s2 = block_sum(s2, lds);
    float rstd = rsqrtf(s2 * (1.f / D) + 1e-5f);
    float dot = 0.f;
    #pragma unroll
    for (int i = 0; i < 3; ++i) {
      int d0 = tid + 256 * i;
      float y = (v[i] - mu) * rstd * g[d0] + b[d0];
      dot += y * hw[d0];
    }
    dot = block_sum(dot, lds);
    logit += dot;
  }
  if (tid == 0) out[n] = logit * (1.f / TT) + hb[0];
}

} // namespace

extern "C" void kernel_launch(void* const* d_in, const int* in_sizes, int n_in,
                              void* d_out, int out_size, void* d_ws, size_t ws_size,
                              hipStream_t stream) {
  const float* x       = (const float*)d_in[0];
  const float* patch_w = (const float*)d_in[1];
  const float* patch_b = (const float*)d_in[2];
  const float* cls     = (const float*)d_in[3];
  const float* pos     = (const float*)d_in[4];
  const float* tim     = (const float*)d_in[5];
  const float* wqkv_s  = (const float*)d_in[6];
  const float* bqkv_s  = (const float*)d_in[7];
  const float* wqkv_t  = (const float*)d_in[8];
  const float* bqkv_t  = (const float*)d_in[9];
  const float* wproj   = (const float*)d_in[10];
  const float* bproj   = (const float*)d_in[11];
  const float* ln_g    = (const float*)d_in[12];
  const float* ln_b    = (const float*)d_in[13];
  const float* head_w  = (const float*)d_in[14];
  const float* head_b  = (const float*)d_in[15];
  float* out = (float*)d_out;

  // ---- workspace layout ----
  char* p = (char*)d_ws;
  float* h = (float*)p;                 p += (size_t)NTOK * D * 4;
  unsigned short* hb = (unsigned short*)p;   p += (size_t)NTOK * D * 2;
  unsigned short* qkvb = (unsigned short*)p; p += (size_t)NTOK * QKVD * 2;
  unsigned short* ob = (unsigned short*)p;   p += (size_t)NTOK * D * 2;
  unsigned short* wsT = (unsigned short*)p;  p += (size_t)12 * QKVD * D * 2;
  unsigned short* wtT = (unsigned short*)p;  p += (size_t)12 * QKVD * D * 2;
  unsigned short* wpT = (unsigned short*)p;  p += (size_t)12 * D * D * 2;
  unsigned short* xpb = qkvb;               // 8192x768 bf16 patch matrix (aliased)
  unsigned short* pwb = ob;                 // 768x768 bf16 patch weights (aliased)
  float* tok = (float*)wsT;                 // 8192x768 fp32 patch-embed out (aliased)

  // ---- patch embed (bf16 MFMA; patch_w is already BT-layout, bias folded in) ----
  unfold_kernel<<<(NPAT * D + 255) / 256, 256, 0, stream>>>(x, xpb);
  cast_pw<<<(D * D + 255) / 256, 256, 0, stream>>>(patch_w, pwb);
  gemm_bf16<<<dim3(D / 128, NPAT / 128), 256, 0, stream>>>(
      xpb, pwb, patch_b, nullptr, tok, nullptr, NPAT, D, 2);
  assemble_kernel<<<(NTOK * D + 255) / 256, 256, 0, stream>>>(tok, cls, pos, tim, h, hb);

  // ---- weights -> transposed bf16 (overwrites tok region; assemble already done) ----
  wconv<<<dim3(QKVD / 32, D / 32, 12), 256, 0, stream>>>(wqkv_s, wsT, QKVD);
  wconv<<<dim3(QKVD / 32, D / 32, 12), 256, 0, stream>>>(wqkv_t, wtT, QKVD);
  wconv<<<dim3(D / 32, D / 32, 12), 256, 0, stream>>>(wproj, wpT, D);

  // ---- transformer layers ----
  const int MB = (NTOK + 127) / 128;     // 65  (128-row tiles, proj)
  const int MB64 = (NTOK + 63) / 64;     // 129 (64-row tiles, qkv)
  for (int l = 0; l < 12; ++l) {
    gemm_bf16_h64<<<dim3(QKVD / 128, MB64), 256, 0, stream>>>(
        hb, wsT + (size_t)l * QKVD * D, bqkv_s + (size_t)l * QKVD,
        qkvb, NTOK, QKVD);
    attn_spatial3<<<NB * TT * NH * 5, 256, 0, stream>>>(qkvb, ob);
    gemm_bf16<<<dim3(D / 128, MB), 256, 0, stream>>>(
        ob, wpT + (size_t)l * D * D, bproj + (size_t)l * D,
        nullptr, h, hb, NTOK, D, 1);

    gemm_bf16_h64<<<dim3(QKVD / 128, MB64), 256, 0, stream>>>(
        hb, wtT + (size_t)l * QKVD * D, bqkv_t + (size_t)l * QKVD,
        qkvb, NTOK, QKVD);
    attn_temporal2<<<(NB * NH * PTOT) / 4, 256, 0, stream>>>(qkvb, ob);
    gemm_bf16<<<dim3(D / 128, MB), 256, 0, stream>>>(
        ob, wpT + (size_t)l * D * D, bproj + (size_t)l * D,
        nullptr, h, hb, NTOK, D, 1);
  }

  // ---- final LN (cls rows only) + temporal mean + head ----
  head_kernel<<<2, 256, 0, stream>>>(h, ln_g, ln_b, head_w, head_b, out);
}

// Round 12
// 2882.880 us; speedup vs baseline: 1.0687x; 1.0687x over previous
//
#include <hip/hip_runtime.h>
#include <hip/hip_bf16.h>
#include <math.h>

namespace {

constexpr int D    = 768;
constexpr int NH   = 12;
constexpr int PTOT = 257;
constexpr int NB   = 2;
constexpr int TT   = 16;
constexpr int NTOK = NB * TT * PTOT;   // 8224
constexpr int NPAT = NB * TT * 256;    // 8192
constexpr int QKVD = 3 * D;            // 2304

typedef short short8  __attribute__((ext_vector_type(8)));
typedef float float4v __attribute__((ext_vector_type(4)));

__device__ __forceinline__ float bf2f(unsigned short u) {
  unsigned v = ((unsigned)u) << 16;
  float f; __builtin_memcpy(&f, &v, 4); return f;
}
__device__ __forceinline__ unsigned short f2bf(float f) {
  unsigned u; __builtin_memcpy(&u, &f, 4);
  u += 0x7FFFu + ((u >> 16) & 1u);   // RNE
  return (unsigned short)(u >> 16);
}

// async global->LDS, 16B per lane, dst = uniform base + lane*16
__device__ __forceinline__ void gload_lds16(const void* g, void* l) {
  __builtin_amdgcn_global_load_lds((const __attribute__((address_space(1))) void*)g,
                                   (__attribute__((address_space(3))) void*)l, 16, 0, 0);
}

// ---------------- unfold x -> xpb (8192 x 768) bf16 ----------------
__global__ __launch_bounds__(256) void unfold_kernel(const float* __restrict__ x,
                                                     unsigned short* __restrict__ xpb) {
  int idx = blockIdx.x * 256 + threadIdx.x;
  if (idx >= NPAT * D) return;
  int f  = idx % D;
  int pg = idx / D;
  int c = f >> 8;
  int r = f & 255;
  int i = r >> 4, j = r & 15;
  int nt = pg >> 8;
  int s  = pg & 255;
  int hp = s >> 4, wp = s & 15;
  xpb[idx] = f2bf(x[(size_t)(nt * 3 + c) * 65536 + (size_t)(hp * 16 + i) * 256 + (wp * 16 + j)]);
}

// ---------------- patch_w (768x768, already BT-layout) fp32 -> bf16 ----------------
__global__ __launch_bounds__(256) void cast_pw(const float* __restrict__ pw,
                                               unsigned short* __restrict__ pwb) {
  int idx = blockIdx.x * 256 + threadIdx.x;
  if (idx >= D * D) return;
  pwb[idx] = f2bf(pw[idx]);
}

// ---------------- weight transpose + fp32->bf16: W[L][768][N] -> WT[L][N][768] ----
__global__ __launch_bounds__(256) void wconv(const float* __restrict__ W,
                                             unsigned short* __restrict__ WT, int N) {
  __shared__ float tile[32][33];
  int l = blockIdx.z;
  const float* w = W + (size_t)l * 768 * N;
  unsigned short* wt = WT + (size_t)l * 768 * N;
  int n0 = blockIdx.x * 32, k0 = blockIdx.y * 32;
  int t = threadIdx.x;
  {
    int r = t >> 3, c4 = (t & 7) * 4;
    float4 v = *(const float4*)(w + (size_t)(k0 + r) * N + n0 + c4);
    tile[r][c4 + 0] = v.x; tile[r][c4 + 1] = v.y;
    tile[r][c4 + 2] = v.z; tile[r][c4 + 3] = v.w;
  }
  __syncthreads();
  {
    int rn = t >> 3, ck = (t & 7) * 4;
    ushort4 o;
    o.x = f2bf(tile[ck + 0][rn]); o.y = f2bf(tile[ck + 1][rn]);
    o.z = f2bf(tile[ck + 2][rn]); o.w = f2bf(tile[ck + 3][rn]);
    *(ushort4*)(wt + (size_t)(n0 + rn) * 768 + k0 + ck) = o;
  }
}

// ---------------- assemble h (fp32) + hb (bf16 mirror) ----------------
// patch_b is already folded into tok by the patch-embed GEMM's bias path.
__global__ __launch_bounds__(256) void assemble_kernel(const float* __restrict__ tok,
    const float* __restrict__ cls,
    const float* __restrict__ pos, const float* __restrict__ tim,
    float* __restrict__ h, unsigned short* __restrict__ hb) {
  int idx = blockIdx.x * 256 + threadIdx.x;
  if (idx >= NTOK * D) return;
  int d = idx % D;
  int tokid = idx / D;
  int p  = tokid % PTOT;
  int nt = tokid / PTOT;
  int t  = nt % TT;
  float v = pos[p * D + d] + tim[t * D + d];
  if (p == 0) v += cls[d];
  else        v += tok[(size_t)(nt * 256 + (p - 1)) * D + d];
  h[idx] = v;
  hb[idx] = f2bf(v);
}

// ---------------- bf16 MFMA GEMM, 2-phase pipelined + XCD swizzle + bounce epilogue --
// C = A(MxK) @ BT(NxK)^T + bias.  K = 768 (24 steps of BK=32).
// mode 0: Cb = result (bf16).  mode 1: Hf += result (fp32); Hb = bf16(new Hf).
// mode 2: Hf = result (fp32).
// STRUCTURAL FLOOR at this shape (K=768, M=8224, N<=2304): six variants A/B'd
// and all regressed vs this 128x128/BK=32/2-phase form -- R3 4-buf counted
// vmcnt (117us), R5 256^2 8-wave (116us), R6 BK=64 (88us), R7 read-swizzle
// (neutral), R10 128x256 (57us), R11 64x128 high-occ (64us). Baseline 55us qkv.
// Deep pipelines need the 8-phase regime which this shape cannot fill.
// LDS-bounce epilogue (R8, -700us total): bf16 stores were 2x write-amplified
// (32B quad segments < 64B granule); bounce via dead As/Bs -> 16B/lane in
// 256B runs. Mode 1 Hf RMW stays direct (64B f32 segments already coalesced).
__global__ __launch_bounds__(256) void gemm_bf16(
    const unsigned short* __restrict__ A,
    const unsigned short* __restrict__ BT,
    const float* __restrict__ bias,
    unsigned short* __restrict__ Cb,
    float* __restrict__ Hf,
    unsigned short* __restrict__ Hb,
    int M, int N, int mode)
{
  constexpr int K = 768;
  constexpr int NT = K / 32;           // 24 K-steps
  __shared__ unsigned short smem[16384];   // 32 KB: As(8K) | Bs(8K) shorts; epilogue: Ct[128][128]
  auto As = (unsigned short (*)[128][32])smem;
  auto Bs = (unsigned short (*)[128][32])(smem + 8192);
  auto Ct = (unsigned short (*)[128])smem;
  int tid = threadIdx.x;

  // bijective XCD-aware remap of the flat (dispatch-order) workgroup id (m204)
  int nwg = gridDim.x * gridDim.y;
  int wg  = blockIdx.y * gridDim.x + blockIdx.x;   // x-fastest dispatch order
  int qq  = nwg >> 3, rr = nwg & 7;
  int xcd = wg & 7, bidx = wg >> 3;
  int newid = (xcd < rr ? xcd * (qq + 1) : rr * (qq + 1) + (xcd - rr) * qq) + bidx;
  int m0 = (newid / gridDim.x) * 128;
  int n0 = (newid % gridDim.x) * 128;

  int w = tid >> 6, lane = tid & 63;
  int quad = lane >> 4, l16 = lane & 15;
  int wm = (w & 1) * 64, wn = (w >> 1) * 64;
  const int lrow = lane >> 2;          // 0..15 within an issue
  const int scol = (lane & 3) * 8;     // shorts
  float4v acc[4][4] = {};

  // hoisted per-lane staging pointers (advance by t*32 shorts per K-step)
  const unsigned short* gA0 = A + (size_t)min(m0 + w * 32 + lrow, M - 1) * K + scol;
  const unsigned short* gA1 = A + (size_t)min(m0 + w * 32 + 16 + lrow, M - 1) * K + scol;
  const unsigned short* gB0 = BT + (size_t)(n0 + w * 32 + lrow) * K + scol;
  const unsigned short* gB1 = BT + (size_t)(n0 + w * 32 + 16 + lrow) * K + scol;

  auto STAGE = [&](int buf, int t) {
    int kk = t * 32;
    gload_lds16(gA0 + kk, &As[buf][w * 32][0]);
    gload_lds16(gA1 + kk, &As[buf][w * 32 + 16][0]);
    gload_lds16(gB0 + kk, &Bs[buf][w * 32][0]);
    gload_lds16(gB1 + kk, &Bs[buf][w * 32 + 16][0]);
  };
  auto COMPUTE = [&](int buf) {
    short8 af[4], bfr[4];
    #pragma unroll
    for (int i = 0; i < 4; ++i) {
      af[i]  = *(const short8*)&As[buf][wm + i * 16 + l16][quad * 8];
      bfr[i] = *(const short8*)&Bs[buf][wn + i * 16 + l16][quad * 8];
    }
    __builtin_amdgcn_s_setprio(1);
    #pragma unroll
    for (int i = 0; i < 4; ++i)
      #pragma unroll
      for (int j = 0; j < 4; ++j)
        acc[i][j] = __builtin_amdgcn_mfma_f32_16x16x32_bf16(af[i], bfr[j], acc[i][j], 0, 0, 0);
    __builtin_amdgcn_s_setprio(0);
  };

  STAGE(0, 0);
  __syncthreads();                       // drains prologue loads
  for (int t = 0; t < NT; t += 2) {
    STAGE(1, t + 1);                     // prefetch next tile (in flight during MFMA)
    COMPUTE(0);
    __syncthreads();                     // drain buf1 loads; all waves done reading buf0
    if (t + 2 < NT) STAGE(0, t + 2);
    COMPUTE(1);
    __syncthreads();                     // drain buf0 loads; all waves done reading buf1
  }

  if (mode == 2) {
    // fp32 direct stores: 16-lane f32 segments = 64B aligned, already coalesced
    #pragma unroll
    for (int j = 0; j < 4; ++j) {
      int col = n0 + wn + j * 16 + l16;
      float bv = bias[col];
      #pragma unroll
      for (int i = 0; i < 4; ++i) {
        #pragma unroll
        for (int r = 0; r < 4; ++r) {
          int row = m0 + wm + i * 16 + quad * 4 + r;
          if (row < M) Hf[(size_t)row * N + col] = acc[i][j][r] + bv;
        }
      }
    }
    return;
  }

  // ---- phase A: fragments -> Ct (quad-XOR chunk swizzle), mode 1 also RMWs Hf ----
  #pragma unroll
  for (int j = 0; j < 4; ++j) {
    int col = wn + j * 16 + l16;                   // tile col 0..127
    float bv = bias[n0 + col];
    int pc = (((col >> 3) ^ quad) << 3) | (col & 7);  // swizzled phys col
    #pragma unroll
    for (int i = 0; i < 4; ++i) {
      #pragma unroll
      for (int r = 0; r < 4; ++r) {
        int row = wm + i * 16 + quad * 4 + r;      // tile row 0..127 ; (row>>2)&3 == quad
        float v = acc[i][j][r] + bv;
        unsigned short ov;
        if (mode == 1) {
          size_t off = (size_t)(m0 + row) * N + (n0 + col);
          if (m0 + row < M) {
            float nv = Hf[off] + v;
            Hf[off] = nv;
            ov = f2bf(nv);
          } else ov = 0;
        } else {
          ov = f2bf(v);
        }
        Ct[row][pc] = ov;
      }
    }
  }
  __syncthreads();
  // ---- phase B: coalesced bounce-out, 16B/lane in 256B-contiguous runs ----
  unsigned short* Ob = (mode == 0) ? Cb : Hb;
  #pragma unroll
  for (int e = 0; e < 8; ++e) {
    int c    = e * 256 + tid;
    int trow = c >> 4, tch = c & 15;
    int grow = m0 + trow;
    if (grow < M) {
      int pch = tch ^ ((trow >> 2) & 3);
      *(uint4*)(Ob + (size_t)grow * N + n0 + tch * 8) = *(const uint4*)&Ct[trow][pch * 8];
    }
  }
}

// ---------------- spatial attention (bf16 MFMA, flash-tiled) ----------------
// R9: one Q-TILE PER BLOCK (grid x5 = 1920; consecutive blocks share (nt,head)
// K/V in L2). Per-wave just-in-time P slice Psl[4][16][72] replaces the 38KB
// full-Ps: LDS 56.3 -> 27.6 KB. V-transpose writes ROTATED per lane
// (conflict-free; was 16-way = 11.1M conflict cycles).
__global__ __launch_bounds__(256) void attn_spatial3(
    const unsigned short* __restrict__ qkv,
    unsigned short* __restrict__ o)
{
  __shared__ unsigned short Qs[64][72];
  __shared__ unsigned short KVs[64][72];   // K rows (QK phase) / V^T dims (PV phase)
  __shared__ unsigned short Psl[4][16][72];  // per-wave P slice for one 64-k V tile
  int tid = threadIdx.x;
  int w = tid >> 6, lane = tid & 63;
  int quad = lane >> 4, l16 = lane & 15;
  int bid = blockIdx.x;
  int bh = bid / 5, qt = bid % 5;          // 5 q-tiles per (nt,head)
  int nt = bh / NH, head = bh % NH;
  int q0 = qt * 64;
  size_t base = (size_t)nt * PTOT;
  const unsigned short* Qg = qkv + head * 64;
  const unsigned short* Kg = qkv + 768 + head * 64;
  const unsigned short* Vg = qkv + 1536 + head * 64;

  // ---- stage Q once (vectorized) ----
  #pragma unroll
  for (int e = 0; e < 2; ++e) {
    int chunk = e * 256 + tid;
    int row = chunk >> 3, off = (chunk & 7) * 8;
    int qr = min(q0 + row, PTOT - 1);
    *(uint4*)&Qs[row][off] = *(const uint4*)(Qg + (base + qr) * (size_t)QKVD + off);
  }
  __syncthreads();
  int qrow = w * 16 + l16;
  short8 qa0 = *(const short8*)&Qs[qrow][quad * 8];
  short8 qa1 = *(const short8*)&Qs[qrow][32 + quad * 8];

  // ---- QK^T: 5 K tiles, scores in registers ----
  float4v st[17];
  #pragma unroll
  for (int kc = 0; kc < 5; ++kc) {
    __syncthreads();
    #pragma unroll
    for (int e = 0; e < 2; ++e) {
      int chunk = e * 256 + tid;
      int row = chunk >> 3, off = (chunk & 7) * 8;
      int kr = min(kc * 64 + row, PTOT - 1);
      *(uint4*)&KVs[row][off] = *(const uint4*)(Kg + (base + kr) * (size_t)QKVD + off);
    }
    __syncthreads();
    #pragma unroll
    for (int tt = 0; tt < 4; ++tt) {
      int t = kc * 4 + tt;
      if (t < 17) {
        short8 kb0 = *(const short8*)&KVs[tt * 16 + l16][quad * 8];
        short8 kb1 = *(const short8*)&KVs[tt * 16 + l16][32 + quad * 8];
        float4v a = {0.f, 0.f, 0.f, 0.f};
        a = __builtin_amdgcn_mfma_f32_16x16x32_bf16(qa0, kb0, a, 0, 0, 0);
        a = __builtin_amdgcn_mfma_f32_16x16x32_bf16(qa1, kb1, a, 0, 0, 0);
        st[t] = a;
      }
    }
  }
  if (l16 >= 1) {
    st[16][0] = -1e30f; st[16][1] = -1e30f; st[16][2] = -1e30f; st[16][3] = -1e30f;
  }
  // ---- softmax (1/8 scale folded into exp; monotone) ----
  float mx[4] = {-1e30f, -1e30f, -1e30f, -1e30f};
  #pragma unroll
  for (int t = 0; t < 17; ++t)
    #pragma unroll
    for (int r = 0; r < 4; ++r) mx[r] = fmaxf(mx[r], st[t][r]);
  #pragma unroll
  for (int off = 1; off < 16; off <<= 1)
    #pragma unroll
    for (int r = 0; r < 4; ++r) mx[r] = fmaxf(mx[r], __shfl_xor(mx[r], off));
  float sm[4] = {0.f, 0.f, 0.f, 0.f};
  #pragma unroll
  for (int t = 0; t < 17; ++t)
    #pragma unroll
    for (int r = 0; r < 4; ++r) {
      float e = __expf((st[t][r] - mx[r]) * 0.125f);
      st[t][r] = e;
      sm[r] += e;
    }
  #pragma unroll
  for (int off = 1; off < 16; off <<= 1)
    #pragma unroll
    for (int r = 0; r < 4; ++r) sm[r] += __shfl_xor(sm[r], off);
  float linv[4];
  #pragma unroll
  for (int r = 0; r < 4; ++r) linv[r] = 1.f / sm[r];

  // ---- PV: 5 V tiles; per-tile JIT P slice (wave-private, no extra barriers) ----
  float4v oacc[4] = {};
  #pragma unroll
  for (int vc = 0; vc < 5; ++vc) {
    __syncthreads();
    // V transposed stage with lane-rotated write order (conflict-free)
    #pragma unroll
    for (int e = 0; e < 2; ++e) {
      int chunk = e * 256 + tid;
      int row = chunk >> 3;
      int oo  = chunk & 7;
      int off = oo * 8;
      int vr = min(vc * 64 + row, PTOT - 1);
      uint4 u = *(const uint4*)(Vg + (base + vr) * (size_t)QKVD + off);
      #pragma unroll
      for (int s = 0; s < 8; ++s) {
        int idx = (oo + s) & 7;
        unsigned sel01 = (idx & 2) ? u.y : u.x;
        unsigned sel23 = (idx & 2) ? u.w : u.z;
        unsigned dw    = (idx & 4) ? sel23 : sel01;
        unsigned short val = (idx & 1) ? (unsigned short)(dw >> 16) : (unsigned short)dw;
        KVs[off + idx][row] = val;
      }
    }
    // P slice for this 64-k tile (wave-private; lgkm ordering suffices)
    #pragma unroll
    for (int tt = 0; tt < 4; ++tt) {
      int t = vc * 4 + tt;
      #pragma unroll
      for (int r = 0; r < 4; ++r) {
        unsigned short pv = 0;
        if (t < 17) pv = f2bf(st[t][r]);
        Psl[w][quad * 4 + r][tt * 16 + l16] = pv;
      }
    }
    __syncthreads();
    int ksmax = (vc == 4) ? 1 : 2;
    #pragma unroll
    for (int ks = 0; ks < 2; ++ks) {
      if (ks < ksmax) {
        short8 pa = *(const short8*)&Psl[w][l16][ks * 32 + quad * 8];
        #pragma unroll
        for (int j = 0; j < 4; ++j) {
          short8 vb = *(const short8*)&KVs[j * 16 + l16][ks * 32 + quad * 8];
          oacc[j] = __builtin_amdgcn_mfma_f32_16x16x32_bf16(pa, vb, oacc[j], 0, 0, 0);
        }
      }
    }
  }
  // ---- store ----
  #pragma unroll
  for (int r = 0; r < 4; ++r) {
    int qg = q0 + w * 16 + quad * 4 + r;
    if (qg < PTOT) {
      #pragma unroll
      for (int j = 0; j < 4; ++j)
        o[(base + qg) * (size_t)D + head * 64 + j * 16 + l16] = f2bf(oacc[j][r] * linv[r]);
    }
  }
}

// ---------------- temporal attention v2: one wave per (n,head,p), MFMA 16x16 ----
// grid = 6168/4 blocks, 4 waves/block, wave-private LDS, NO barriers.
__global__ __launch_bounds__(256) void attn_temporal2(const unsigned short* __restrict__ qkv,
                                                      unsigned short* __restrict__ o) {
  __shared__ unsigned short Ps[4][16][32];   // P padded to K=32 (cols 16..31 zero)
  __shared__ unsigned short VT[4][64][32];   // V^T padded to K=32
  int tid = threadIdx.x;
  int w = tid >> 6, lane = tid & 63;
  int quad = lane >> 4, l16 = lane & 15;
  int s = blockIdx.x * 4 + w;                // 0..6167
  int p  = s % PTOT;
  int nh = s / PTOT;
  int n = nh / NH, head = nh % NH;

  // zero k-padding (wave-local)
  {
    ushort4 z = {0, 0, 0, 0};
    *(ushort4*)&Ps[w][lane >> 2][16 + (lane & 3) * 4] = z;
    *(uint4*)&VT[w][lane][16] = (uint4){0, 0, 0, 0};
    *(uint4*)&VT[w][lane][24] = (uint4){0, 0, 0, 0};
  }

  const size_t rstride = (size_t)PTOT * QKVD;   // elements between consecutive t
  const unsigned short* base0 = qkv + ((size_t)(n * TT) * PTOT + p) * QKVD + head * 64;

  // Q/K fragments straight from global (row t = l16, 16B chunks)
  const unsigned short* qrow = base0 + (size_t)l16 * rstride;
  short8 qa0 = *(const short8*)(qrow + quad * 8);
  short8 qa1 = *(const short8*)(qrow + 32 + quad * 8);
  const unsigned short* krow = qrow + 768;
  short8 kb0 = *(const short8*)(krow + quad * 8);
  short8 kb1 = *(const short8*)(krow + 32 + quad * 8);

  float4v sc = {0.f, 0.f, 0.f, 0.f};
  sc = __builtin_amdgcn_mfma_f32_16x16x32_bf16(qa0, kb0, sc, 0, 0, 0);
  sc = __builtin_amdgcn_mfma_f32_16x16x32_bf16(qa1, kb1, sc, 0, 0, 0);

  // softmax across the 16 lanes of each quad (rows quad*4+r, cols l16)
  float e4[4], mx[4], sm[4];
  #pragma unroll
  for (int r = 0; r < 4; ++r) mx[r] = sc[r] * 0.125f;
  #pragma unroll
  for (int off = 1; off < 16; off <<= 1)
    #pragma unroll
    for (int r = 0; r < 4; ++r) mx[r] = fmaxf(mx[r], __shfl_xor(mx[r], off));
  #pragma unroll
  for (int r = 0; r < 4; ++r) { e4[r] = __expf(sc[r] * 0.125f - mx[r]); sm[r] = e4[r]; }
  #pragma unroll
  for (int off = 1; off < 16; off <<= 1)
    #pragma unroll
    for (int r = 0; r < 4; ++r) sm[r] += __shfl_xor(sm[r], off);
  float linv[4];
  #pragma unroll
  for (int r = 0; r < 4; ++r) linv[r] = 1.f / sm[r];

  // P -> LDS (A-layout source)
  #pragma unroll
  for (int r = 0; r < 4; ++r) Ps[w][quad * 4 + r][l16] = f2bf(e4[r]);

  // V^T -> LDS: lane covers V row t'=l16, dims quad*16..quad*16+15
  {
    const unsigned short* vrow = qrow + 1536 + quad * 16;
    uint4 v0 = *(const uint4*)vrow;
    uint4 v1 = *(const uint4*)(vrow + 8);
    const unsigned short* pv0 = (const unsigned short*)&v0;
    const unsigned short* pv1 = (const unsigned short*)&v1;
    #pragma unroll
    for (int i = 0; i < 8; ++i) VT[w][quad * 16 + i][l16]     = pv0[i];
    #pragma unroll
    for (int i = 0; i < 8; ++i) VT[w][quad * 16 + 8 + i][l16] = pv1[i];
  }

  // PV: O[16 q][64 d] = P @ V, 4 MFMAs over d-tiles
  short8 pa = *(const short8*)&Ps[w][l16][quad * 8];
  float4v oacc[4];
  #pragma unroll
  for (int j = 0; j < 4; ++j) {
    short8 vb = *(const short8*)&VT[w][j * 16 + l16][quad * 8];
    float4v z = {0.f, 0.f, 0.f, 0.f};
    oacc[j] = __builtin_amdgcn_mfma_f32_16x16x32_bf16(pa, vb, z, 0, 0, 0);
  }

  // store: row t = quad*4+r, col head*64 + j*16 + l16
  #pragma unroll
  for (int r = 0; r < 4; ++r) {
    size_t orow = ((size_t)(n * TT + quad * 4 + r) * PTOT + p) * D + head * 64;
    #pragma unroll
    for (int j = 0; j < 4; ++j)
      o[orow + j * 16 + l16] = f2bf(oacc[j][r] * linv[r]);
  }
}

// ---------------- final LN + head, parallelized over (n,t) ----------------
// R12: old head_kernel ran 2 blocks with 16 serial iterations x 3 barrier
// reductions (serial tail on a 256-CU chip). head1: 32 blocks, one cls row
// each (LN + dot). head2: 1 block, 16-lane shfl reduce per batch.
__device__ __forceinline__ float block_sum(float v, float* lds) {
  #pragma unroll
  for (int off = 32; off; off >>= 1) v += __shfl_down(v, off);
  __syncthreads();
  if ((threadIdx.x & 63) == 0) lds[threadIdx.x >> 6] = v;
  __syncthreads();
  return lds[0] + lds[1] + lds[2] + lds[3];
}

__global__ __launch_bounds__(256) void head1_kernel(const float* __restrict__ h,
    const float* __restrict__ g, const float* __restrict__ b,
    const float* __restrict__ hw, float* __restrict__ scratch) {
  __shared__ float lds[4];
  int nt = blockIdx.x, tid = threadIdx.x;     // nt = n*TT + t, 0..31
  const float* row = h + (size_t)(nt * PTOT) * D;
  float v[3]; float s = 0.f;
  #pragma unroll
  for (int i = 0; i < 3; ++i) { v[i] = row[tid + 256 * i]; s += v[i]; }
  s = block_sum(s, lds);
  float mu = s * (1.f / D);
  float s2 = 0.f;
  #pragma unroll
  for (int i = 0; i < 3; ++i) { float d0 = v[i] - mu; s2 += d0 * d0; }
  s2 = block_sum(s2, lds);
  float rstd = rsqrtf(s2 * (1.f / D) + 1e-5f);
  float dot = 0.f;
  #pragma unroll
  for (int i = 0; i < 3; ++i) {
    int d0 = tid + 256 * i;
    float y = (v[i] - mu) * rstd * g[d0] + b[d0];
    dot += y * hw[d0];
  }
  dot = block_sum(dot, lds);
  if (tid == 0) scratch[nt] = dot;
}

__global__ __launch_bounds__(64) void head2_kernel(const float* __restrict__ scratch,
    const float* __restrict__ hb_, float* __restrict__ out) {
  int lane = threadIdx.x;
  float v = (lane < NB * TT) ? scratch[lane] : 0.f;
  #pragma unroll
  for (int off = 1; off < 16; off <<= 1) v += __shfl_xor(v, off);   // within 16-lane group
  if (lane == 0)  out[0] = v * (1.f / TT) + hb_[0];
  if (lane == 16) out[1] = v * (1.f / TT) + hb_[0];
}

} // namespace

extern "C" void kernel_launch(void* const* d_in, const int* in_sizes, int n_in,
                              void* d_out, int out_size, void* d_ws, size_t ws_size,
                              hipStream_t stream) {
  const float* x       = (const float*)d_in[0];
  const float* patch_w = (const float*)d_in[1];
  const float* patch_b = (const float*)d_in[2];
  const float* cls     = (const float*)d_in[3];
  const float* pos     = (const float*)d_in[4];
  const float* tim     = (const float*)d_in[5];
  const float* wqkv_s  = (const float*)d_in[6];
  const float* bqkv_s  = (const float*)d_in[7];
  const float* wqkv_t  = (const float*)d_in[8];
  const float* bqkv_t  = (const float*)d_in[9];
  const float* wproj   = (const float*)d_in[10];
  const float* bproj   = (const float*)d_in[11];
  const float* ln_g    = (const float*)d_in[12];
  const float* ln_b    = (const float*)d_in[13];
  const float* head_w  = (const float*)d_in[14];
  const float* head_b  = (const float*)d_in[15];
  float* out = (float*)d_out;

  // ---- workspace layout ----
  char* p = (char*)d_ws;
  float* h = (float*)p;                 p += (size_t)NTOK * D * 4;
  unsigned short* hb = (unsigned short*)p;   p += (size_t)NTOK * D * 2;
  unsigned short* qkvb = (unsigned short*)p; p += (size_t)NTOK * QKVD * 2;
  unsigned short* ob = (unsigned short*)p;   p += (size_t)NTOK * D * 2;
  unsigned short* wsT = (unsigned short*)p;  p += (size_t)12 * QKVD * D * 2;
  unsigned short* wtT = (unsigned short*)p;  p += (size_t)12 * QKVD * D * 2;
  unsigned short* wpT = (unsigned short*)p;  p += (size_t)12 * D * D * 2;
  unsigned short* xpb = qkvb;               // 8192x768 bf16 patch matrix (aliased)
  unsigned short* pwb = ob;                 // 768x768 bf16 patch weights (aliased)
  float* tok = (float*)wsT;                 // 8192x768 fp32 patch-embed out (aliased)
  float* scratch = (float*)ob;              // 32 floats; ob is dead after last proj

  // ---- patch embed (bf16 MFMA; patch_w is already BT-layout, bias folded in) ----
  unfold_kernel<<<(NPAT * D + 255) / 256, 256, 0, stream>>>(x, xpb);
  cast_pw<<<(D * D + 255) / 256, 256, 0, stream>>>(patch_w, pwb);
  gemm_bf16<<<dim3(D / 128, NPAT / 128), 256, 0, stream>>>(
      xpb, pwb, patch_b, nullptr, tok, nullptr, NPAT, D, 2);
  assemble_kernel<<<(NTOK * D + 255) / 256, 256, 0, stream>>>(tok, cls, pos, tim, h, hb);

  // ---- weights -> transposed bf16 (overwrites tok region; assemble already done) ----
  wconv<<<dim3(QKVD / 32, D / 32, 12), 256, 0, stream>>>(wqkv_s, wsT, QKVD);
  wconv<<<dim3(QKVD / 32, D / 32, 12), 256, 0, stream>>>(wqkv_t, wtT, QKVD);
  wconv<<<dim3(D / 32, D / 32, 12), 256, 0, stream>>>(wproj, wpT, D);

  // ---- transformer layers ----
  const int MB = (NTOK + 127) / 128;   // 65
  for (int l = 0; l < 12; ++l) {
    gemm_bf16<<<dim3(QKVD / 128, MB), 256, 0, stream>>>(
        hb, wsT + (size_t)l * QKVD * D, bqkv_s + (size_t)l * QKVD,
        qkvb, nullptr, nullptr, NTOK, QKVD, 0);
    attn_spatial3<<<NB * TT * NH * 5, 256, 0, stream>>>(qkvb, ob);
    gemm_bf16<<<dim3(D / 128, MB), 256, 0, stream>>>(
        ob, wpT + (size_t)l * D * D, bproj + (size_t)l * D,
        nullptr, h, hb, NTOK, D, 1);

    gemm_bf16<<<dim3(QKVD / 128, MB), 256, 0, stream>>>(
        hb, wtT + (size_t)l * QKVD * D, bqkv_t + (size_t)l * QKVD,
        qkvb, nullptr, nullptr, NTOK, QKVD, 0);
    attn_temporal2<<<(NB * NH * PTOT) / 4, 256, 0, stream>>>(qkvb, ob);
    gemm_bf16<<<dim3(D / 128, MB), 256, 0, stream>>>(
        ob, wpT + (size_t)l * D * D, bproj + (size_t)l * D,
        nullptr, h, hb, NTOK, D, 1);
  }

  // ---- final LN (cls rows only) + temporal mean + head ----
  head1_kernel<<<NB * TT, 256, 0, stream>>>(h, ln_g, ln_b, head_w, scratch);
  head2_kernel<<<1, 64, 0, stream>>>(scratch, head_b, out);
}

// Round 13
// 2760.584 us; speedup vs baseline: 1.1160x; 1.0443x over previous
//
#include <hip/hip_runtime.h>
#include <hip/hip_bf16.h>
#include <math.h>

namespace {

constexpr int D    = 768;
constexpr int NH   = 12;
constexpr int PTOT = 257;
constexpr int NB   = 2;
constexpr int TT   = 16;
constexpr int NTOK = NB * TT * PTOT;   // 8224
constexpr int NPAT = NB * TT * 256;    // 8192
constexpr int QKVD = 3 * D;            // 2304

typedef short short8  __attribute__((ext_vector_type(8)));
typedef float float4v __attribute__((ext_vector_type(4)));

__device__ __forceinline__ float bf2f(unsigned short u) {
  unsigned v = ((unsigned)u) << 16;
  float f; __builtin_memcpy(&f, &v, 4); return f;
}
__device__ __forceinline__ unsigned short f2bf(float f) {
  unsigned u; __builtin_memcpy(&u, &f, 4);
  u += 0x7FFFu + ((u >> 16) & 1u);   // RNE
  return (unsigned short)(u >> 16);
}

// async global->LDS, 16B per lane, dst = uniform base + lane*16
__device__ __forceinline__ void gload_lds16(const void* g, void* l) {
  __builtin_amdgcn_global_load_lds((const __attribute__((address_space(1))) void*)g,
                                   (__attribute__((address_space(3))) void*)l, 16, 0, 0);
}

// ---------------- unfold x -> xpb (8192 x 768) bf16 ----------------
__global__ __launch_bounds__(256) void unfold_kernel(const float* __restrict__ x,
                                                     unsigned short* __restrict__ xpb) {
  int idx = blockIdx.x * 256 + threadIdx.x;
  if (idx >= NPAT * D) return;
  int f  = idx % D;
  int pg = idx / D;
  int c = f >> 8;
  int r = f & 255;
  int i = r >> 4, j = r & 15;
  int nt = pg >> 8;
  int s  = pg & 255;
  int hp = s >> 4, wp = s & 15;
  xpb[idx] = f2bf(x[(size_t)(nt * 3 + c) * 65536 + (size_t)(hp * 16 + i) * 256 + (wp * 16 + j)]);
}

// ---------------- patch_w (768x768, already BT-layout) fp32 -> bf16 ----------------
__global__ __launch_bounds__(256) void cast_pw(const float* __restrict__ pw,
                                               unsigned short* __restrict__ pwb) {
  int idx = blockIdx.x * 256 + threadIdx.x;
  if (idx >= D * D) return;
  pwb[idx] = f2bf(pw[idx]);
}

// ---------------- weight transpose + fp32->bf16: W[L][768][N] -> WT[L][N][768] ----
__global__ __launch_bounds__(256) void wconv(const float* __restrict__ W,
                                             unsigned short* __restrict__ WT, int N) {
  __shared__ float tile[32][33];
  int l = blockIdx.z;
  const float* w = W + (size_t)l * 768 * N;
  unsigned short* wt = WT + (size_t)l * 768 * N;
  int n0 = blockIdx.x * 32, k0 = blockIdx.y * 32;
  int t = threadIdx.x;
  {
    int r = t >> 3, c4 = (t & 7) * 4;
    float4 v = *(const float4*)(w + (size_t)(k0 + r) * N + n0 + c4);
    tile[r][c4 + 0] = v.x; tile[r][c4 + 1] = v.y;
    tile[r][c4 + 2] = v.z; tile[r][c4 + 3] = v.w;
  }
  __syncthreads();
  {
    int rn = t >> 3, ck = (t & 7) * 4;
    ushort4 o;
    o.x = f2bf(tile[ck + 0][rn]); o.y = f2bf(tile[ck + 1][rn]);
    o.z = f2bf(tile[ck + 2][rn]); o.w = f2bf(tile[ck + 3][rn]);
    *(ushort4*)(wt + (size_t)(n0 + rn) * 768 + k0 + ck) = o;
  }
}

// ---------------- assemble h (fp32) + hb (bf16 mirror) ----------------
// patch_b is already folded into tok by the patch-embed GEMM's bias path.
__global__ __launch_bounds__(256) void assemble_kernel(const float* __restrict__ tok,
    const float* __restrict__ cls,
    const float* __restrict__ pos, const float* __restrict__ tim,
    float* __restrict__ h, unsigned short* __restrict__ hb) {
  int idx = blockIdx.x * 256 + threadIdx.x;
  if (idx >= NTOK * D) return;
  int d = idx % D;
  int tokid = idx / D;
  int p  = tokid % PTOT;
  int nt = tokid / PTOT;
  int t  = nt % TT;
  float v = pos[p * D + d] + tim[t * D + d];
  if (p == 0) v += cls[d];
  else        v += tok[(size_t)(nt * 256 + (p - 1)) * D + d];
  h[idx] = v;
  hb[idx] = f2bf(v);
}

// ---------------- bf16 MFMA GEMM, 2-phase pipelined + XCD swizzle + bounce epilogue --
// C = A(MxK) @ BT(NxK)^T + bias.  K = 768 (24 steps of BK=32).
// mode 0: Cb = result (bf16).  mode 1: Hf += result (fp32); Hb = bf16(new Hf).
// mode 2: Hf = result (fp32).
// Proven floor for proj/patch shapes. See gemm_bf16_p3 for the qkv variant.
__global__ __launch_bounds__(256) void gemm_bf16(
    const unsigned short* __restrict__ A,
    const unsigned short* __restrict__ BT,
    const float* __restrict__ bias,
    unsigned short* __restrict__ Cb,
    float* __restrict__ Hf,
    unsigned short* __restrict__ Hb,
    int M, int N, int mode)
{
  constexpr int K = 768;
  constexpr int NT = K / 32;           // 24 K-steps
  __shared__ unsigned short smem[16384];   // 32 KB: As(8K) | Bs(8K) shorts; epilogue: Ct[128][128]
  auto As = (unsigned short (*)[128][32])smem;
  auto Bs = (unsigned short (*)[128][32])(smem + 8192);
  auto Ct = (unsigned short (*)[128])smem;
  int tid = threadIdx.x;

  // bijective XCD-aware remap of the flat (dispatch-order) workgroup id (m204)
  int nwg = gridDim.x * gridDim.y;
  int wg  = blockIdx.y * gridDim.x + blockIdx.x;   // x-fastest dispatch order
  int qq  = nwg >> 3, rr = nwg & 7;
  int xcd = wg & 7, bidx = wg >> 3;
  int newid = (xcd < rr ? xcd * (qq + 1) : rr * (qq + 1) + (xcd - rr) * qq) + bidx;
  int m0 = (newid / gridDim.x) * 128;
  int n0 = (newid % gridDim.x) * 128;

  int w = tid >> 6, lane = tid & 63;
  int quad = lane >> 4, l16 = lane & 15;
  int wm = (w & 1) * 64, wn = (w >> 1) * 64;
  const int lrow = lane >> 2;          // 0..15 within an issue
  const int scol = (lane & 3) * 8;     // shorts
  float4v acc[4][4] = {};

  // hoisted per-lane staging pointers (advance by t*32 shorts per K-step)
  const unsigned short* gA0 = A + (size_t)min(m0 + w * 32 + lrow, M - 1) * K + scol;
  const unsigned short* gA1 = A + (size_t)min(m0 + w * 32 + 16 + lrow, M - 1) * K + scol;
  const unsigned short* gB0 = BT + (size_t)(n0 + w * 32 + lrow) * K + scol;
  const unsigned short* gB1 = BT + (size_t)(n0 + w * 32 + 16 + lrow) * K + scol;

  auto STAGE = [&](int buf, int t) {
    int kk = t * 32;
    gload_lds16(gA0 + kk, &As[buf][w * 32][0]);
    gload_lds16(gA1 + kk, &As[buf][w * 32 + 16][0]);
    gload_lds16(gB0 + kk, &Bs[buf][w * 32][0]);
    gload_lds16(gB1 + kk, &Bs[buf][w * 32 + 16][0]);
  };
  auto COMPUTE = [&](int buf) {
    short8 af[4], bfr[4];
    #pragma unroll
    for (int i = 0; i < 4; ++i) {
      af[i]  = *(const short8*)&As[buf][wm + i * 16 + l16][quad * 8];
      bfr[i] = *(const short8*)&Bs[buf][wn + i * 16 + l16][quad * 8];
    }
    __builtin_amdgcn_s_setprio(1);
    #pragma unroll
    for (int i = 0; i < 4; ++i)
      #pragma unroll
      for (int j = 0; j < 4; ++j)
        acc[i][j] = __builtin_amdgcn_mfma_f32_16x16x32_bf16(af[i], bfr[j], acc[i][j], 0, 0, 0);
    __builtin_amdgcn_s_setprio(0);
  };

  STAGE(0, 0);
  __syncthreads();                       // drains prologue loads
  for (int t = 0; t < NT; t += 2) {
    STAGE(1, t + 1);                     // prefetch next tile (in flight during MFMA)
    COMPUTE(0);
    __syncthreads();                     // drain buf1 loads; all waves done reading buf0
    if (t + 2 < NT) STAGE(0, t + 2);
    COMPUTE(1);
    __syncthreads();                     // drain buf0 loads; all waves done reading buf1
  }

  if (mode == 2) {
    // fp32 direct stores: 16-lane f32 segments = 64B aligned, already coalesced
    #pragma unroll
    for (int j = 0; j < 4; ++j) {
      int col = n0 + wn + j * 16 + l16;
      float bv = bias[col];
      #pragma unroll
      for (int i = 0; i < 4; ++i) {
        #pragma unroll
        for (int r = 0; r < 4; ++r) {
          int row = m0 + wm + i * 16 + quad * 4 + r;
          if (row < M) Hf[(size_t)row * N + col] = acc[i][j][r] + bv;
        }
      }
    }
    return;
  }

  // ---- phase A: fragments -> Ct (quad-XOR chunk swizzle), mode 1 also RMWs Hf ----
  #pragma unroll
  for (int j = 0; j < 4; ++j) {
    int col = wn + j * 16 + l16;                   // tile col 0..127
    float bv = bias[n0 + col];
    int pc = (((col >> 3) ^ quad) << 3) | (col & 7);  // swizzled phys col
    #pragma unroll
    for (int i = 0; i < 4; ++i) {
      #pragma unroll
      for (int r = 0; r < 4; ++r) {
        int row = wm + i * 16 + quad * 4 + r;      // tile row 0..127 ; (row>>2)&3 == quad
        float v = acc[i][j][r] + bv;
        unsigned short ov;
        if (mode == 1) {
          size_t off = (size_t)(m0 + row) * N + (n0 + col);
          if (m0 + row < M) {
            float nv = Hf[off] + v;
            Hf[off] = nv;
            ov = f2bf(nv);
          } else ov = 0;
        } else {
          ov = f2bf(v);
        }
        Ct[row][pc] = ov;
      }
    }
  }
  __syncthreads();
  // ---- phase B: coalesced bounce-out, 16B/lane in 256B-contiguous runs ----
  unsigned short* Ob = (mode == 0) ? Cb : Hb;
  #pragma unroll
  for (int e = 0; e < 8; ++e) {
    int c    = e * 256 + tid;
    int trow = c >> 4, tch = c & 15;
    int grow = m0 + trow;
    if (grow < M) {
      int pch = tch ^ ((trow >> 2) & 3);
      *(uint4*)(Ob + (size_t)grow * N + n0 + tch * 8) = *(const uint4*)&Ct[trow][pch * 8];
    }
  }
}

// ---------------- qkv GEMM: 3-buffer counted-vmcnt pipeline (mode-0 only) ---------
// R13: LAST unexplored cell of the structure matrix. Counted-vmcnt was tested at
// 64KB/4-buf (R3: occupancy cliff) and 256^2/128KB (R5: grid quantization) but
// never at the 48KB/3-buf point that keeps LDS cap at 3 blocks/CU. Each stage is
// in flight for TWO compute phases + a barrier (~600-1000 cyc >= HBM latency) vs
// the 2-phase kernel's single phase then forced drain. Wait mechanics proven
// correct in R3/R5 (both passed): vmcnt(4) -> raw s_barrier -> STAGE(t+2) ->
// COMPUTE(t); vmcnt(0) only at the final step. Buffer (t+2)%3 last read at
// COMPUTE(t-1), separated by the iter-t barrier -> safe.
// PRE-COMMIT: if qkv >= 55us this reverts next round and the plateau is final.
__global__ __launch_bounds__(256) void gemm_bf16_p3(
    const unsigned short* __restrict__ A,
    const unsigned short* __restrict__ BT,
    const float* __restrict__ bias,
    unsigned short* __restrict__ Cb,
    int M, int N)
{
  constexpr int K = 768;
  constexpr int NT = K / 32;           // 24 K-steps
  __shared__ unsigned short smem[24576];   // 48 KB: As[3][128][32] | Bs[3][128][32]
  auto As = (unsigned short (*)[128][32])smem;
  auto Bs = (unsigned short (*)[128][32])(smem + 12288);
  auto Ct = (unsigned short (*)[128])smem;  // epilogue reuse (32 KB of the 48)
  int tid = threadIdx.x;

  int nwg = gridDim.x * gridDim.y;
  int wg  = blockIdx.y * gridDim.x + blockIdx.x;
  int qq  = nwg >> 3, rr = nwg & 7;
  int xcd = wg & 7, bidx = wg >> 3;
  int newid = (xcd < rr ? xcd * (qq + 1) : rr * (qq + 1) + (xcd - rr) * qq) + bidx;
  int m0 = (newid / gridDim.x) * 128;
  int n0 = (newid % gridDim.x) * 128;

  int w = tid >> 6, lane = tid & 63;
  int quad = lane >> 4, l16 = lane & 15;
  int wm = (w & 1) * 64, wn = (w >> 1) * 64;
  const int lrow = lane >> 2;
  const int scol = (lane & 3) * 8;
  float4v acc[4][4] = {};

  const unsigned short* gA0 = A + (size_t)min(m0 + w * 32 + lrow, M - 1) * K + scol;
  const unsigned short* gA1 = A + (size_t)min(m0 + w * 32 + 16 + lrow, M - 1) * K + scol;
  const unsigned short* gB0 = BT + (size_t)(n0 + w * 32 + lrow) * K + scol;
  const unsigned short* gB1 = BT + (size_t)(n0 + w * 32 + 16 + lrow) * K + scol;

  auto STAGE = [&](int buf, int t) {
    int kk = t * 32;
    gload_lds16(gA0 + kk, &As[buf][w * 32][0]);
    gload_lds16(gA1 + kk, &As[buf][w * 32 + 16][0]);
    gload_lds16(gB0 + kk, &Bs[buf][w * 32][0]);
    gload_lds16(gB1 + kk, &Bs[buf][w * 32 + 16][0]);
  };
  auto COMPUTE = [&](int buf) {
    short8 af[4], bfr[4];
    #pragma unroll
    for (int i = 0; i < 4; ++i) {
      af[i]  = *(const short8*)&As[buf][wm + i * 16 + l16][quad * 8];
      bfr[i] = *(const short8*)&Bs[buf][wn + i * 16 + l16][quad * 8];
    }
    __builtin_amdgcn_s_setprio(1);
    #pragma unroll
    for (int i = 0; i < 4; ++i)
      #pragma unroll
      for (int j = 0; j < 4; ++j)
        acc[i][j] = __builtin_amdgcn_mfma_f32_16x16x32_bf16(af[i], bfr[j], acc[i][j], 0, 0, 0);
    __builtin_amdgcn_s_setprio(0);
  };
  // one K-step: own stage(t) landed (vmcnt<=4), all waves synced, issue t+2, compute t
  auto STEP = [&](int t, int buf, int bufp2) {
    if (t < NT - 1) { asm volatile("s_waitcnt vmcnt(4)" ::: "memory"); }
    else            { asm volatile("s_waitcnt vmcnt(0)" ::: "memory"); }
    __builtin_amdgcn_s_barrier();
    asm volatile("" ::: "memory");
    if (t + 2 < NT) STAGE(bufp2, t + 2);
    COMPUTE(buf);
  };

  STAGE(0, 0);
  STAGE(1, 1);
  #pragma unroll 1
  for (int t0 = 0; t0 < NT; t0 += 3) {   // NT = 24, divisible by 3
    STEP(t0 + 0, 0, 2);
    STEP(t0 + 1, 1, 0);
    STEP(t0 + 2, 2, 1);
  }
  __builtin_amdgcn_sched_barrier(0);
  __syncthreads();                       // all waves done reading smem as As/Bs

  // ---- bounce epilogue (mode-0): fragments -> Ct (quad-XOR) -> coalesced out ----
  #pragma unroll
  for (int j = 0; j < 4; ++j) {
    int col = wn + j * 16 + l16;
    float bv = bias[n0 + col];
    int pc = (((col >> 3) ^ quad) << 3) | (col & 7);
    #pragma unroll
    for (int i = 0; i < 4; ++i) {
      #pragma unroll
      for (int r = 0; r < 4; ++r) {
        int row = wm + i * 16 + quad * 4 + r;
        Ct[row][pc] = f2bf(acc[i][j][r] + bv);
      }
    }
  }
  __syncthreads();
  #pragma unroll
  for (int e = 0; e < 8; ++e) {
    int c    = e * 256 + tid;
    int trow = c >> 4, tch = c & 15;
    int grow = m0 + trow;
    if (grow < M) {
      int pch = tch ^ ((trow >> 2) & 3);
      *(uint4*)(Cb + (size_t)grow * N + n0 + tch * 8) = *(const uint4*)&Ct[trow][pch * 8];
    }
  }
}

// ---------------- spatial attention (bf16 MFMA, flash-tiled) ----------------
// R9: one Q-TILE PER BLOCK (grid x5 = 1920; consecutive blocks share (nt,head)
// K/V in L2). Per-wave just-in-time P slice Psl[4][16][72] replaces the 38KB
// full-Ps: LDS 56.3 -> 27.6 KB. V-transpose writes ROTATED per lane
// (conflict-free; was 16-way = 11.1M conflict cycles).
__global__ __launch_bounds__(256) void attn_spatial3(
    const unsigned short* __restrict__ qkv,
    unsigned short* __restrict__ o)
{
  __shared__ unsigned short Qs[64][72];
  __shared__ unsigned short KVs[64][72];   // K rows (QK phase) / V^T dims (PV phase)
  __shared__ unsigned short Psl[4][16][72];  // per-wave P slice for one 64-k V tile
  int tid = threadIdx.x;
  int w = tid >> 6, lane = tid & 63;
  int quad = lane >> 4, l16 = lane & 15;
  int bid = blockIdx.x;
  int bh = bid / 5, qt = bid % 5;          // 5 q-tiles per (nt,head)
  int nt = bh / NH, head = bh % NH;
  int q0 = qt * 64;
  size_t base = (size_t)nt * PTOT;
  const unsigned short* Qg = qkv + head * 64;
  const unsigned short* Kg = qkv + 768 + head * 64;
  const unsigned short* Vg = qkv + 1536 + head * 64;

  // ---- stage Q once (vectorized) ----
  #pragma unroll
  for (int e = 0; e < 2; ++e) {
    int chunk = e * 256 + tid;
    int row = chunk >> 3, off = (chunk & 7) * 8;
    int qr = min(q0 + row, PTOT - 1);
    *(uint4*)&Qs[row][off] = *(const uint4*)(Qg + (base + qr) * (size_t)QKVD + off);
  }
  __syncthreads();
  int qrow = w * 16 + l16;
  short8 qa0 = *(const short8*)&Qs[qrow][quad * 8];
  short8 qa1 = *(const short8*)&Qs[qrow][32 + quad * 8];

  // ---- QK^T: 5 K tiles, scores in registers ----
  float4v st[17];
  #pragma unroll
  for (int kc = 0; kc < 5; ++kc) {
    __syncthreads();
    #pragma unroll
    for (int e = 0; e < 2; ++e) {
      int chunk = e * 256 + tid;
      int row = chunk >> 3, off = (chunk & 7) * 8;
      int kr = min(kc * 64 + row, PTOT - 1);
      *(uint4*)&KVs[row][off] = *(const uint4*)(Kg + (base + kr) * (size_t)QKVD + off);
    }
    __syncthreads();
    #pragma unroll
    for (int tt = 0; tt < 4; ++tt) {
      int t = kc * 4 + tt;
      if (t < 17) {
        short8 kb0 = *(const short8*)&KVs[tt * 16 + l16][quad * 8];
        short8 kb1 = *(const short8*)&KVs[tt * 16 + l16][32 + quad * 8];
        float4v a = {0.f, 0.f, 0.f, 0.f};
        a = __builtin_amdgcn_mfma_f32_16x16x32_bf16(qa0, kb0, a, 0, 0, 0);
        a = __builtin_amdgcn_mfma_f32_16x16x32_bf16(qa1, kb1, a, 0, 0, 0);
        st[t] = a;
      }
    }
  }
  if (l16 >= 1) {
    st[16][0] = -1e30f; st[16][1] = -1e30f; st[16][2] = -1e30f; st[16][3] = -1e30f;
  }
  // ---- softmax (1/8 scale folded into exp; monotone) ----
  float mx[4] = {-1e30f, -1e30f, -1e30f, -1e30f};
  #pragma unroll
  for (int t = 0; t < 17; ++t)
    #pragma unroll
    for (int r = 0; r < 4; ++r) mx[r] = fmaxf(mx[r], st[t][r]);
  #pragma unroll
  for (int off = 1; off < 16; off <<= 1)
    #pragma unroll
    for (int r = 0; r < 4; ++r) mx[r] = fmaxf(mx[r], __shfl_xor(mx[r], off));
  float sm[4] = {0.f, 0.f, 0.f, 0.f};
  #pragma unroll
  for (int t = 0; t < 17; ++t)
    #pragma unroll
    for (int r = 0; r < 4; ++r) {
      float e = __expf((st[t][r] - mx[r]) * 0.125f);
      st[t][r] = e;
      sm[r] += e;
    }
  #pragma unroll
  for (int off = 1; off < 16; off <<= 1)
    #pragma unroll
    for (int r = 0; r < 4; ++r) sm[r] += __shfl_xor(sm[r], off);
  float linv[4];
  #pragma unroll
  for (int r = 0; r < 4; ++r) linv[r] = 1.f / sm[r];

  // ---- PV: 5 V tiles; per-tile JIT P slice (wave-private, no extra barriers) ----
  float4v oacc[4] = {};
  #pragma unroll
  for (int vc = 0; vc < 5; ++vc) {
    __syncthreads();
    // V transposed stage with lane-rotated write order (conflict-free)
    #pragma unroll
    for (int e = 0; e < 2; ++e) {
      int chunk = e * 256 + tid;
      int row = chunk >> 3;
      int oo  = chunk & 7;
      int off = oo * 8;
      int vr = min(vc * 64 + row, PTOT - 1);
      uint4 u = *(const uint4*)(Vg + (base + vr) * (size_t)QKVD + off);
      #pragma unroll
      for (int s = 0; s < 8; ++s) {
        int idx = (oo + s) & 7;
        unsigned sel01 = (idx & 2) ? u.y : u.x;
        unsigned sel23 = (idx & 2) ? u.w : u.z;
        unsigned dw    = (idx & 4) ? sel23 : sel01;
        unsigned short val = (idx & 1) ? (unsigned short)(dw >> 16) : (unsigned short)dw;
        KVs[off + idx][row] = val;
      }
    }
    // P slice for this 64-k tile (wave-private; lgkm ordering suffices)
    #pragma unroll
    for (int tt = 0; tt < 4; ++tt) {
      int t = vc * 4 + tt;
      #pragma unroll
      for (int r = 0; r < 4; ++r) {
        unsigned short pv = 0;
        if (t < 17) pv = f2bf(st[t][r]);
        Psl[w][quad * 4 + r][tt * 16 + l16] = pv;
      }
    }
    __syncthreads();
    int ksmax = (vc == 4) ? 1 : 2;
    #pragma unroll
    for (int ks = 0; ks < 2; ++ks) {
      if (ks < ksmax) {
        short8 pa = *(const short8*)&Psl[w][l16][ks * 32 + quad * 8];
        #pragma unroll
        for (int j = 0; j < 4; ++j) {
          short8 vb = *(const short8*)&KVs[j * 16 + l16][ks * 32 + quad * 8];
          oacc[j] = __builtin_amdgcn_mfma_f32_16x16x32_bf16(pa, vb, oacc[j], 0, 0, 0);
        }
      }
    }
  }
  // ---- store ----
  #pragma unroll
  for (int r = 0; r < 4; ++r) {
    int qg = q0 + w * 16 + quad * 4 + r;
    if (qg < PTOT) {
      #pragma unroll
      for (int j = 0; j < 4; ++j)
        o[(base + qg) * (size_t)D + head * 64 + j * 16 + l16] = f2bf(oacc[j][r] * linv[r]);
    }
  }
}

// ---------------- temporal attention v2: one wave per (n,head,p), MFMA 16x16 ----
// grid = 6168/4 blocks, 4 waves/block, wave-private LDS, NO barriers.
__global__ __launch_bounds__(256) void attn_temporal2(const unsigned short* __restrict__ qkv,
                                                      unsigned short* __restrict__ o) {
  __shared__ unsigned short Ps[4][16][32];   // P padded to K=32 (cols 16..31 zero)
  __shared__ unsigned short VT[4][64][32];   // V^T padded to K=32
  int tid = threadIdx.x;
  int w = tid >> 6, lane = tid & 63;
  int quad = lane >> 4, l16 = lane & 15;
  int s = blockIdx.x * 4 + w;                // 0..6167
  int p  = s % PTOT;
  int nh = s / PTOT;
  int n = nh / NH, head = nh % NH;

  // zero k-padding (wave-local)
  {
    ushort4 z = {0, 0, 0, 0};
    *(ushort4*)&Ps[w][lane >> 2][16 + (lane & 3) * 4] = z;
    *(uint4*)&VT[w][lane][16] = (uint4){0, 0, 0, 0};
    *(uint4*)&VT[w][lane][24] = (uint4){0, 0, 0, 0};
  }

  const size_t rstride = (size_t)PTOT * QKVD;   // elements between consecutive t
  const unsigned short* base0 = qkv + ((size_t)(n * TT) * PTOT + p) * QKVD + head * 64;

  // Q/K fragments straight from global (row t = l16, 16B chunks)
  const unsigned short* qrow = base0 + (size_t)l16 * rstride;
  short8 qa0 = *(const short8*)(qrow + quad * 8);
  short8 qa1 = *(const short8*)(qrow + 32 + quad * 8);
  const unsigned short* krow = qrow + 768;
  short8 kb0 = *(const short8*)(krow + quad * 8);
  short8 kb1 = *(const short8*)(krow + 32 + quad * 8);

  float4v sc = {0.f, 0.f, 0.f, 0.f};
  sc = __builtin_amdgcn_mfma_f32_16x16x32_bf16(qa0, kb0, sc, 0, 0, 0);
  sc = __builtin_amdgcn_mfma_f32_16x16x32_bf16(qa1, kb1, sc, 0, 0, 0);

  // softmax across the 16 lanes of each quad (rows quad*4+r, cols l16)
  float e4[4], mx[4], sm[4];
  #pragma unroll
  for (int r = 0; r < 4; ++r) mx[r] = sc[r] * 0.125f;
  #pragma unroll
  for (int off = 1; off < 16; off <<= 1)
    #pragma unroll
    for (int r = 0; r < 4; ++r) mx[r] = fmaxf(mx[r], __shfl_xor(mx[r], off));
  #pragma unroll
  for (int r = 0; r < 4; ++r) { e4[r] = __expf(sc[r] * 0.125f - mx[r]); sm[r] = e4[r]; }
  #pragma unroll
  for (int off = 1; off < 16; off <<= 1)
    #pragma unroll
    for (int r = 0; r < 4; ++r) sm[r] += __shfl_xor(sm[r], off);
  float linv[4];
  #pragma unroll
  for (int r = 0; r < 4; ++r) linv[r] = 1.f / sm[r];

  // P -> LDS (A-layout source)
  #pragma unroll
  for (int r = 0; r < 4; ++r) Ps[w][quad * 4 + r][l16] = f2bf(e4[r]);

  // V^T -> LDS: lane covers V row t'=l16, dims quad*16..quad*16+15
  {
    const unsigned short* vrow = qrow + 1536 + quad * 16;
    uint4 v0 = *(const uint4*)vrow;
    uint4 v1 = *(const uint4*)(vrow + 8);
    const unsigned short* pv0 = (const unsigned short*)&v0;
    const unsigned short* pv1 = (const unsigned short*)&v1;
    #pragma unroll
    for (int i = 0; i < 8; ++i) VT[w][quad * 16 + i][l16]     = pv0[i];
    #pragma unroll
    for (int i = 0; i < 8; ++i) VT[w][quad * 16 + 8 + i][l16] = pv1[i];
  }

  // PV: O[16 q][64 d] = P @ V, 4 MFMAs over d-tiles
  short8 pa = *(const short8*)&Ps[w][l16][quad * 8];
  float4v oacc[4];
  #pragma unroll
  for (int j = 0; j < 4; ++j) {
    short8 vb = *(const short8*)&VT[w][j * 16 + l16][quad * 8];
    float4v z = {0.f, 0.f, 0.f, 0.f};
    oacc[j] = __builtin_amdgcn_mfma_f32_16x16x32_bf16(pa, vb, z, 0, 0, 0);
  }

  // store: row t = quad*4+r, col head*64 + j*16 + l16
  #pragma unroll
  for (int r = 0; r < 4; ++r) {
    size_t orow = ((size_t)(n * TT + quad * 4 + r) * PTOT + p) * D + head * 64;
    #pragma unroll
    for (int j = 0; j < 4; ++j)
      o[orow + j * 16 + l16] = f2bf(oacc[j][r] * linv[r]);
  }
}

// ---------------- final LN + head, parallelized over (n,t) ----------------
__device__ __forceinline__ float block_sum(float v, float* lds) {
  #pragma unroll
  for (int off = 32; off; off >>= 1) v += __shfl_down(v, off);
  __syncthreads();
  if ((threadIdx.x & 63) == 0) lds[threadIdx.x >> 6] = v;
  __syncthreads();
  return lds[0] + lds[1] + lds[2] + lds[3];
}

__global__ __launch_bounds__(256) void head1_kernel(const float* __restrict__ h,
    const float* __restrict__ g, const float* __restrict__ b,
    const float* __restrict__ hw, float* __restrict__ scratch) {
  __shared__ float lds[4];
  int nt = blockIdx.x, tid = threadIdx.x;     // nt = n*TT + t, 0..31
  const float* row = h + (size_t)(nt * PTOT) * D;
  float v[3]; float s = 0.f;
  #pragma unroll
  for (int i = 0; i < 3; ++i) { v[i] = row[tid + 256 * i]; s += v[i]; }
  s = block_sum(s, lds);
  float mu = s * (1.f / D);
  float s2 = 0.f;
  #pragma unroll
  for (int i = 0; i < 3; ++i) { float d0 = v[i] - mu; s2 += d0 * d0; }
  s2 = block_sum(s2, lds);
  float rstd = rsqrtf(s2 * (1.f / D) + 1e-5f);
  float dot = 0.f;
  #pragma unroll
  for (int i = 0; i < 3; ++i) {
    int d0 = tid + 256 * i;
    float y = (v[i] - mu) * rstd * g[d0] + b[d0];
    dot += y * hw[d0];
  }
  dot = block_sum(dot, lds);
  if (tid == 0) scratch[nt] = dot;
}

__global__ __launch_bounds__(64) void head2_kernel(const float* __restrict__ scratch,
    const float* __restrict__ hb_, float* __restrict__ out) {
  int lane = threadIdx.x;
  float v = (lane < NB * TT) ? scratch[lane] : 0.f;
  #pragma unroll
  for (int off = 1; off < 16; off <<= 1) v += __shfl_xor(v, off);   // within 16-lane group
  if (lane == 0)  out[0] = v * (1.f / TT) + hb_[0];
  if (lane == 16) out[1] = v * (1.f / TT) + hb_[0];
}

} // namespace

extern "C" void kernel_launch(void* const* d_in, const int* in_sizes, int n_in,
                              void* d_out, int out_size, void* d_ws, size_t ws_size,
                              hipStream_t stream) {
  const float* x       = (const float*)d_in[0];
  const float* patch_w = (const float*)d_in[1];
  const float* patch_b = (const float*)d_in[2];
  const float* cls     = (const float*)d_in[3];
  const float* pos     = (const float*)d_in[4];
  const float* tim     = (const float*)d_in[5];
  const float* wqkv_s  = (const float*)d_in[6];
  const float* bqkv_s  = (const float*)d_in[7];
  const float* wqkv_t  = (const float*)d_in[8];
  const float* bqkv_t  = (const float*)d_in[9];
  const float* wproj   = (const float*)d_in[10];
  const float* bproj   = (const float*)d_in[11];
  const float* ln_g    = (const float*)d_in[12];
  const float* ln_b    = (const float*)d_in[13];
  const float* head_w  = (const float*)d_in[14];
  const float* head_b  = (const float*)d_in[15];
  float* out = (float*)d_out;

  // ---- workspace layout ----
  char* p = (char*)d_ws;
  float* h = (float*)p;                 p += (size_t)NTOK * D * 4;
  unsigned short* hb = (unsigned short*)p;   p += (size_t)NTOK * D * 2;
  unsigned short* qkvb = (unsigned short*)p; p += (size_t)NTOK * QKVD * 2;
  unsigned short* ob = (unsigned short*)p;   p += (size_t)NTOK * D * 2;
  unsigned short* wsT = (unsigned short*)p;  p += (size_t)12 * QKVD * D * 2;
  unsigned short* wtT = (unsigned short*)p;  p += (size_t)12 * QKVD * D * 2;
  unsigned short* wpT = (unsigned short*)p;  p += (size_t)12 * D * D * 2;
  unsigned short* xpb = qkvb;               // 8192x768 bf16 patch matrix (aliased)
  unsigned short* pwb = ob;                 // 768x768 bf16 patch weights (aliased)
  float* tok = (float*)wsT;                 // 8192x768 fp32 patch-embed out (aliased)
  float* scratch = (float*)ob;              // 32 floats; ob is dead after last proj

  // ---- patch embed (bf16 MFMA; patch_w is already BT-layout, bias folded in) ----
  unfold_kernel<<<(NPAT * D + 255) / 256, 256, 0, stream>>>(x, xpb);
  cast_pw<<<(D * D + 255) / 256, 256, 0, stream>>>(patch_w, pwb);
  gemm_bf16<<<dim3(D / 128, NPAT / 128), 256, 0, stream>>>(
      xpb, pwb, patch_b, nullptr, tok, nullptr, NPAT, D, 2);
  assemble_kernel<<<(NTOK * D + 255) / 256, 256, 0, stream>>>(tok, cls, pos, tim, h, hb);

  // ---- weights -> transposed bf16 (overwrites tok region; assemble already done) ----
  wconv<<<dim3(QKVD / 32, D / 32, 12), 256, 0, stream>>>(wqkv_s, wsT, QKVD);
  wconv<<<dim3(QKVD / 32, D / 32, 12), 256, 0, stream>>>(wqkv_t, wtT, QKVD);
  wconv<<<dim3(D / 32, D / 32, 12), 256, 0, stream>>>(wproj, wpT, D);

  // ---- transformer layers ----
  const int MB = (NTOK + 127) / 128;   // 65
  for (int l = 0; l < 12; ++l) {
    gemm_bf16_p3<<<dim3(QKVD / 128, MB), 256, 0, stream>>>(
        hb, wsT + (size_t)l * QKVD * D, bqkv_s + (size_t)l * QKVD,
        qkvb, NTOK, QKVD);
    attn_spatial3<<<NB * TT * NH * 5, 256, 0, stream>>>(qkvb, ob);
    gemm_bf16<<<dim3(D / 128, MB), 256, 0, stream>>>(
        ob, wpT + (size_t)l * D * D, bproj + (size_t)l * D,
        nullptr, h, hb, NTOK, D, 1);

    gemm_bf16_p3<<<dim3(QKVD / 128, MB), 256, 0, stream>>>(
        hb, wtT + (size_t)l * QKVD * D, bqkv_t + (size_t)l * QKVD,
        qkvb, NTOK, QKVD);
    attn_temporal2<<<(NB * NH * PTOT) / 4, 256, 0, stream>>>(qkvb, ob);
    gemm_bf16<<<dim3(D / 128, MB), 256, 0, stream>>>(
        ob, wpT + (size_t)l * D * D, bproj + (size_t)l * D,
        nullptr, h, hb, NTOK, D, 1);
  }

  // ---- final LN (cls rows only) + temporal mean + head ----
  head1_kernel<<<NB * TT, 256, 0, stream>>>(h, ln_g, ln_b, head_w, scratch);
  head2_kernel<<<1, 64, 0, stream>>>(scratch, head_b, out);
}